// Round 2
// baseline (399.382 us; speedup 1.0000x reference)
//
#include <hip/hip_runtime.h>
#include <math.h>

#define D_MODEL 1024
#define SEQ 2048
#define NTOK 4096

typedef __attribute__((ext_vector_type(8))) short bf16x8;
typedef __attribute__((ext_vector_type(4))) float f32x4;

__device__ __forceinline__ unsigned short f2bf(float f) {
    union { float f; unsigned u; } v; v.f = f;
    unsigned r = v.u + 0x7FFFu + ((v.u >> 16) & 1u);   // RNE
    return (unsigned short)(r >> 16);
}
__device__ __forceinline__ float bf2f(unsigned short u) {
    union { unsigned u; float f; } v; v.u = ((unsigned)u) << 16; return v.f;
}
// pack two fp32 -> bf16x2 in one VALU op (RNE). dst.lo = x, dst.hi = y.
__device__ __forceinline__ unsigned cvt_pk_bf16(float x, float y) {
    unsigned r;
    asm("v_cvt_pk_bf16_f32 %0, %1, %2" : "=v"(r) : "v"(x), "v"(y));
    return r;
}

// async global->LDS, 16B per lane. LDS dest must be wave-uniform base + lane*16.
__device__ __forceinline__ void ld_g2l(const void* g, void* l) {
    __builtin_amdgcn_global_load_lds(
        (const __attribute__((address_space(1))) void*)g,
        (__attribute__((address_space(3))) void*)l, 16, 0, 0);
}

// ---------------------------------------------------------------------------
// prep_weights: ONE dispatch does all 6 fp32[K,N]->bf16[N,K] transposes
// plus silu(cond)->bf16.
// ---------------------------------------------------------------------------
__global__ __launch_bounds__(256) void prep_weights(
    const float* __restrict__ p1, const float* __restrict__ p2,
    const float* __restrict__ qkvw, const float* __restrict__ attnw,
    const float* __restrict__ f1, const float* __restrict__ f2,
    const float* __restrict__ cond,
    unsigned short* __restrict__ wt_cond, unsigned short* __restrict__ wt_qkv,
    unsigned short* __restrict__ wt_attn, unsigned short* __restrict__ wt_ffn1,
    unsigned short* __restrict__ wt_ffn2, unsigned short* __restrict__ siluc)
{
    const int t = blockIdx.x;
    if (t >= 3584) {   // silu path: 512 blocks x 1024 float4
        const int base = (t - 3584) * 1024 + threadIdx.x;
#pragma unroll
        for (int i = 0; i < 4; i++) {
            const int idx = base + i * 256;
            float4 v = ((const float4*)cond)[idx];
            ushort4 o;
            o.x = f2bf(v.x / (1.f + expf(-v.x)));
            o.y = f2bf(v.y / (1.f + expf(-v.y)));
            o.z = f2bf(v.z / (1.f + expf(-v.z)));
            o.w = f2bf(v.w / (1.f + expf(-v.w)));
            ((ushort4*)siluc)[idx] = o;
        }
        return;
    }
    const float* src; unsigned short* dst; int K, N, lt;
    if (t < 512)       { src = (t < 256) ? p1 : p2;
                         dst = wt_cond + (t < 256 ? 0 : 2048 * 512);
                         K = 512;  N = 2048; lt = t & 255; }
    else if (t < 1280) { src = qkvw;  dst = wt_qkv;  K = 1024; N = 3072; lt = t - 512; }
    else if (t < 1536) { src = attnw; dst = wt_attn; K = 1024; N = 1024; lt = t - 1280; }
    else if (t < 2560) { src = f1;    dst = wt_ffn1; K = 1024; N = 4096; lt = t - 1536; }
    else               { src = f2;    dst = wt_ffn2; K = 4096; N = 1024; lt = t - 2560; }
    const int ntile = N >> 6;
    const int n0 = (lt % ntile) * 64, k0 = (lt / ntile) * 64;

    __shared__ float tile[64][65];
    const int tx = threadIdx.x & 15, ty = threadIdx.x >> 4;
#pragma unroll
    for (int i = 0; i < 4; i++) {
        const int k = ty + i * 16;
        float4 v = *(const float4*)&src[(size_t)(k0 + k) * N + n0 + tx * 4];
        tile[k][tx * 4 + 0] = v.x; tile[k][tx * 4 + 1] = v.y;
        tile[k][tx * 4 + 2] = v.z; tile[k][tx * 4 + 3] = v.w;
    }
    __syncthreads();
#pragma unroll
    for (int i = 0; i < 4; i++) {
        const int n = ty + i * 16;
        ushort4 o;
        o.x = f2bf(tile[tx * 4 + 0][n]); o.y = f2bf(tile[tx * 4 + 1][n]);
        o.z = f2bf(tile[tx * 4 + 2][n]); o.w = f2bf(tile[tx * 4 + 3][n]);
        *(ushort4*)&dst[(size_t)(n0 + n) * K + k0 + tx * 4] = o;
    }
}

// ---------------------------------------------------------------------------
// bf16 MFMA GEMM: C = epi(A[M,K] @ Bt[N,K]^T). BM x 128 tile, BK=64,
// 4 waves (2x2), 16x16x32 MFMA, global_load_lds staging, XOR swizzle.
// SPLIT>1: grid.z splits K into SPLIT slices; EPI_PART writes bf16 partials.
// ---------------------------------------------------------------------------
#define EPI_GB   0
#define EPI_QKV  1
#define EPI_PROJ 2
#define EPI_FFN1 3
#define EPI_FFN2 4
#define EPI_PART 5

template<int EPI, int BM, int SPLIT = 1>
__global__ __launch_bounds__(256, 4) void gemm_bf16(
    const unsigned short* __restrict__ A,
    const unsigned short* __restrict__ Bt,
    const float* __restrict__ bias, const float* __restrict__ bias2,
    const float* __restrict__ res,
    void* __restrict__ Cv,
    unsigned short* __restrict__ qb, unsigned short* __restrict__ kb,
    unsigned short* __restrict__ vtb,
    int K)
{
    constexpr int WM = BM / 2;     // 64 or 32
    constexpr int MT = WM / 16;    // 4 or 2
    __shared__ __align__(16) unsigned short As[BM * 64];
    __shared__ __align__(16) unsigned short Bs[128 * 64];
    const int tid = threadIdx.x;
    const int lane = tid & 63, w = tid >> 6;
    const int cc = lane & 15, quad = lane >> 4;
    const int wm = (w >> 1) * WM, wn = (w & 1) * 64;
    const int m0 = blockIdx.y * BM, n0 = blockIdx.x * 128;
    const int kslice = K / SPLIT;
    const int kbeg = (SPLIT > 1) ? (int)blockIdx.z * kslice : 0;

    f32x4 acc[MT][4];
#pragma unroll
    for (int i = 0; i < MT; i++)
#pragma unroll
        for (int j = 0; j < 4; j++) acc[i][j] = (f32x4)0.f;

    for (int k0 = kbeg; k0 < kbeg + kslice; k0 += 64) {
        __syncthreads();
#pragma unroll
        for (int i = 0; i < BM / 32; i++) {
            const int idx = i * 256 + tid;
            const int row = idx >> 3, c = idx & 7;
            const int kc = (c ^ (row & 7)) << 3;
            ld_g2l(&A[(size_t)(m0 + row) * K + k0 + kc], &As[idx << 3]);
        }
#pragma unroll
        for (int i = 0; i < 4; i++) {
            const int idx = i * 256 + tid;
            const int row = idx >> 3, c = idx & 7;
            const int kc = (c ^ (row & 7)) << 3;
            ld_g2l(&Bt[(size_t)(n0 + row) * K + k0 + kc], &Bs[idx << 3]);
        }
        __syncthreads();
#pragma unroll
        for (int ks = 0; ks < 2; ks++) {
            bf16x8 af[MT], bfr[4];
            const int pc = (((ks << 2) | quad) ^ (cc & 7)) << 3;
#pragma unroll
            for (int t = 0; t < MT; t++)
                af[t]  = *(const bf16x8*)&As[(wm + t * 16 + cc) * 64 + pc];
#pragma unroll
            for (int t = 0; t < 4; t++)
                bfr[t] = *(const bf16x8*)&Bs[(wn + t * 16 + cc) * 64 + pc];
#pragma unroll
            for (int mt = 0; mt < MT; mt++)
#pragma unroll
                for (int nt = 0; nt < 4; nt++)
                    acc[mt][nt] = __builtin_amdgcn_mfma_f32_16x16x32_bf16(
                        af[mt], bfr[nt], acc[mt][nt], 0, 0, 0);
        }
    }

    // ---- epilogues. C-frag: row = quad*4+r, col = cc ----
    if (EPI == EPI_GB) {
        unsigned short* C = (unsigned short*)Cv;
#pragma unroll
        for (int mt = 0; mt < MT; mt++)
#pragma unroll
        for (int r = 0; r < 4; r++) {
            const int m = m0 + wm + mt * 16 + quad * 4 + r;
#pragma unroll
            for (int nt = 0; nt < 4; nt++) {
                const int n = n0 + wn + nt * 16 + cc;
                const float b = (n < 2048) ? bias[n] : bias2[n - 2048];
                C[(size_t)m * 4096 + n] = f2bf(acc[mt][nt][r] + b);
            }
        }
    } else if (EPI == EPI_PROJ) {
        float* C = (float*)Cv;
#pragma unroll
        for (int mt = 0; mt < MT; mt++)
#pragma unroll
        for (int r = 0; r < 4; r++) {
            const int m = m0 + wm + mt * 16 + quad * 4 + r;
#pragma unroll
            for (int nt = 0; nt < 4; nt++) {
                const int n = n0 + wn + nt * 16 + cc;
                C[(size_t)m * 1024 + n] = acc[mt][nt][r] + res[(size_t)m * 1024 + n];
            }
        }
    } else if (EPI == EPI_FFN1) {
        unsigned short* C = (unsigned short*)Cv;
#pragma unroll
        for (int mt = 0; mt < MT; mt++)
#pragma unroll
        for (int r = 0; r < 4; r++) {
            const int m = m0 + wm + mt * 16 + quad * 4 + r;
#pragma unroll
            for (int nt = 0; nt < 4; nt++) {
                const int n = n0 + wn + nt * 16 + cc;
                float v = acc[mt][nt][r] + bias[n];
                // tanh-approx GELU: x / (1 + exp2(-2.3022084*(x + 0.044715 x^3)))
                const float u = v + 0.044715f * v * v * v;
                const float g = v / (1.f + exp2f(-2.3022084f * u));
                C[(size_t)m * 4096 + n] = f2bf(g);
            }
        }
    } else if (EPI == EPI_PART) {
        // bf16 partial: Cv + z * M*1024
        unsigned short* C = (unsigned short*)Cv + (size_t)blockIdx.z * (4096ull * 1024ull);
#pragma unroll
        for (int mt = 0; mt < MT; mt++)
#pragma unroll
        for (int r = 0; r < 4; r++) {
            const int m = m0 + wm + mt * 16 + quad * 4 + r;
#pragma unroll
            for (int nt = 0; nt < 4; nt++) {
                const int n = n0 + wn + nt * 16 + cc;
                C[(size_t)m * 1024 + n] = f2bf(acc[mt][nt][r]);
            }
        }
    } else if (EPI == EPI_FFN2) {
        float* C = (float*)Cv;
#pragma unroll
        for (int mt = 0; mt < MT; mt++)
#pragma unroll
        for (int r = 0; r < 4; r++) {
            const int m = m0 + wm + mt * 16 + quad * 4 + r;
#pragma unroll
            for (int nt = 0; nt < 4; nt++) {
                const int n = n0 + wn + nt * 16 + cc;
                C[(size_t)m * 1024 + n] = acc[mt][nt][r] + bias[n] + res[(size_t)m * 1024 + n];
            }
        }
    } else {  // EPI_QKV: N=3072, split q/k bf16 + PERMUTED v^T bf16
        const int region = n0 >> 10;
        const int b = m0 >> 11;
        if (region < 2) {
            unsigned short* dst = region ? kb : qb;
            // Q prescale folds softmax 1/sqrt(d) AND log2(e)
            const float sc = region ? 1.0f : 0.125f * 1.44269504088896340736f;
#pragma unroll
            for (int mt = 0; mt < MT; mt++)
#pragma unroll
            for (int r = 0; r < 4; r++) {
                const int m = m0 + wm + mt * 16 + quad * 4 + r;
                const int s = m & 2047;
#pragma unroll
                for (int nt = 0; nt < 4; nt++) {
                    const int n = (n0 + wn + nt * 16 + cc) & 1023;
                    const int hh = n >> 6, d = n & 63;
                    dst[(((size_t)b * 16 + hh) * 2048 + s) * 64 + d] =
                        f2bf(acc[mt][nt][r] * sc);
                }
            }
        } else {
            // V^T stored pre-permuted into PV B-fragment key order
            const int sb = (m0 + wm) & 2047;
#pragma unroll
            for (int mt = 0; mt < MT; mt++) {
                const int kpos = sb + ((mt >> 1) << 5) + (quad << 3) + ((mt & 1) << 2);
#pragma unroll
                for (int nt = 0; nt < 4; nt++) {
                    const int n = (n0 + wn + nt * 16 + cc) & 1023;
                    const int hh = n >> 6, d = n & 63;
                    ushort4 o;
                    o.x = f2bf(acc[mt][nt][0]); o.y = f2bf(acc[mt][nt][1]);
                    o.z = f2bf(acc[mt][nt][2]); o.w = f2bf(acc[mt][nt][3]);
                    *(ushort4*)&vtb[(((size_t)b * 16 + hh) * 64 + d) * 2048 + kpos] = o;
                }
            }
        }
    }
}

// ---------------------------------------------------------------------------
// merge_ffn2: out = x1 + b2 + sum_z P[z]   (P bf16 partials, out fp32)
// ---------------------------------------------------------------------------
__global__ __launch_bounds__(256) void merge_ffn2(
    const unsigned short* __restrict__ P, const float* __restrict__ x1,
    const float* __restrict__ b2, float* __restrict__ out)
{
    const size_t idx = (size_t)blockIdx.x * 1024 + (size_t)threadIdx.x * 4;
    const int n = (int)(idx & 1023);
    float4 xv = *(const float4*)&x1[idx];
    float4 bv = *(const float4*)&b2[n];
    float s0 = 0.f, s1 = 0.f, s2 = 0.f, s3 = 0.f;
#pragma unroll
    for (int z = 0; z < 4; z++) {
        ushort4 p = *(const ushort4*)&P[z * (4096ull * 1024ull) + idx];
        s0 += bf2f(p.x); s1 += bf2f(p.y); s2 += bf2f(p.z); s3 += bf2f(p.w);
    }
    float4 o;
    o.x = xv.x + bv.x + s0;
    o.y = xv.y + bv.y + s1;
    o.z = xv.z + bv.z + s2;
    o.w = xv.w + bv.w + s3;
    *(float4*)&out[idx] = o;
}

// ---------------------------------------------------------------------------
// Transposed MFMA flash attention (v4 structure, zero-conflict), split-K x4:
// z in {0,1,2,3}, 512 keys each. 8 waves x 32 q = 256-q tile.
// Static-max exp2 softmax; partial O (bf16, unscaled) + partial l out.
// P->bf16 via v_cvt_pk_bf16_f32; l via all-ones-A MFMA on the matrix pipe.
// ---------------------------------------------------------------------------
__global__ __launch_bounds__(512) void attn_mfma(
    const unsigned short* __restrict__ qb, const unsigned short* __restrict__ kb,
    const unsigned short* __restrict__ vtb,
    unsigned short* __restrict__ Op0, unsigned short* __restrict__ Op1,
    unsigned short* __restrict__ Op2, unsigned short* __restrict__ Op3,
    float* __restrict__ lp)
{
    __shared__ __align__(16) unsigned short ks[64 * 64];   // [key][d] swizzled
    __shared__ __align__(16) unsigned short vts[64 * 64];  // [d][pos] swizzled

    const int tid = threadIdx.x;
    const int lane = tid & 63, w = tid >> 6;           // 8 waves
    const int c = lane & 15, quad = lane >> 4;
    const int bh = blockIdx.y;
    const int q0 = blockIdx.x * 256;
    const int z = blockIdx.z;
    const int kk0 = z * 512;

    // Q as B-operand: lane needs Q[q0+w*32+qs*16+c][kh*32+quad*8+j]
    bf16x8 qf[2][2];   // [qs][kh]
#pragma unroll
    for (int qs = 0; qs < 2; qs++) {
        const size_t base = (((size_t)bh * 2048) + q0 + w * 32 + qs * 16 + c) * 64 + quad * 8;
        qf[qs][0] = *(const bf16x8*)&qb[base];
        qf[qs][1] = *(const bf16x8*)&qb[base + 32];
    }

    // all-ones bf16 A-operand for the l (row-sum) MFMA
    bf16x8 ones;
#pragma unroll
    for (int i = 0; i < 8; i++) ones[i] = (short)0x3F80;

    f32x4 of[2][4];
#pragma unroll
    for (int qs = 0; qs < 2; qs++)
#pragma unroll
        for (int i = 0; i < 4; i++) of[qs][i] = (f32x4)0.f;
    f32x4 lf[2];
    lf[0] = (f32x4)0.f; lf[1] = (f32x4)0.f;

    const size_t kbase = ((size_t)bh * 2048) * 64;
    const size_t vbase = ((size_t)bh * 64) * 2048;

    // stage addressing: 512 chunks of 16B per tile, one per thread
    const int srow = tid >> 3, spc = tid & 7;
    const int slc = spc ^ (srow & 7);

    for (int kk = kk0; kk < kk0 + 512; kk += 64) {
        __syncthreads();
        ld_g2l(&kb[kbase + (size_t)(kk + srow) * 64 + slc * 8], &ks[tid << 3]);
        ld_g2l(&vtb[vbase + (size_t)srow * 2048 + kk + slc * 8], &vts[tid << 3]);
        __syncthreads();

        // ---- S^T = K @ Q^T ----
        f32x4 sc[2][4];
#pragma unroll
        for (int qs = 0; qs < 2; qs++)
#pragma unroll
            for (int t = 0; t < 4; t++) sc[qs][t] = (f32x4)0.f;
#pragma unroll
        for (int t = 0; t < 4; t++) {
#pragma unroll
            for (int kh = 0; kh < 2; kh++) {
                const int phys = ((kh * 4 + quad) ^ (c & 7)) << 3;
                bf16x8 kf = *(const bf16x8*)&ks[(t * 16 + c) * 64 + phys];
#pragma unroll
                for (int qs = 0; qs < 2; qs++)
                    sc[qs][t] = __builtin_amdgcn_mfma_f32_16x16x32_bf16(
                        kf, qf[qs][kh], sc[qs][t], 0, 0, 0);
            }
        }

        // ---- softmax: static max, exp2 domain; pack via v_cvt_pk_bf16_f32 ----
        bf16x8 pb[2][2];
#pragma unroll
        for (int qs = 0; qs < 2; qs++) {
#pragma unroll
            for (int t = 0; t < 4; t++)
#pragma unroll
                for (int r = 0; r < 4; r++)
                    sc[qs][t][r] = exp2f(sc[qs][t][r]);
#pragma unroll
            for (int kh = 0; kh < 2; kh++) {
                union { int4 i; bf16x8 v; } u;
                u.i.x = cvt_pk_bf16(sc[qs][2 * kh][0],     sc[qs][2 * kh][1]);
                u.i.y = cvt_pk_bf16(sc[qs][2 * kh][2],     sc[qs][2 * kh][3]);
                u.i.z = cvt_pk_bf16(sc[qs][2 * kh + 1][0], sc[qs][2 * kh + 1][1]);
                u.i.w = cvt_pk_bf16(sc[qs][2 * kh + 1][2], sc[qs][2 * kh + 1][3]);
                pb[qs][kh] = u.v;
            }
        }

        // ---- l[q] on the matrix pipe: ones(16x32) @ P^T -> every row = colsum ----
#pragma unroll
        for (int qs = 0; qs < 2; qs++)
#pragma unroll
            for (int kh = 0; kh < 2; kh++)
                lf[qs] = __builtin_amdgcn_mfma_f32_16x16x32_bf16(
                    ones, pb[qs][kh], lf[qs], 0, 0, 0);

        // ---- O^T += V^T @ P^T ----
#pragma unroll
        for (int dt = 0; dt < 4; dt++) {
#pragma unroll
            for (int kh = 0; kh < 2; kh++) {
                const int phys = ((kh * 4 + quad) ^ (c & 7)) << 3;
                bf16x8 vf = *(const bf16x8*)&vts[(dt * 16 + c) * 64 + phys];
#pragma unroll
                for (int qs = 0; qs < 2; qs++)
                    of[qs][dt] = __builtin_amdgcn_mfma_f32_16x16x32_bf16(
                        vf, pb[qs][kh], of[qs][dt], 0, 0, 0);
            }
        }
    }

    // ---- epilogue: store UNSCALED partial O (bf16) + partial l ----
    unsigned short* Op = (z == 0) ? Op0 : (z == 1) ? Op1 : (z == 2) ? Op2 : Op3;
    const int b = bh >> 4, hh = bh & 15;
#pragma unroll
    for (int qs = 0; qs < 2; qs++) {
        const int q = q0 + w * 32 + qs * 16 + c;
        if (lane < 16)
            lp[((size_t)z * 32 + bh) * 2048 + q] = lf[qs][0];
        const size_t row = (size_t)(b * 2048 + q);
#pragma unroll
        for (int dt = 0; dt < 4; dt++) {
            ushort4 o;
            o.x = f2bf(of[qs][dt][0]); o.y = f2bf(of[qs][dt][1]);
            o.z = f2bf(of[qs][dt][2]); o.w = f2bf(of[qs][dt][3]);
            *(ushort4*)&Op[row * 1024 + hh * 64 + dt * 16 + quad * 4] = o;
        }
    }
}

// ---------------------------------------------------------------------------
// merge_attn: attnb = (Op0+Op1+Op2+Op3) / (l0+l1+l2+l3), bf16 out.
// ---------------------------------------------------------------------------
__global__ __launch_bounds__(256) void merge_attn(
    const unsigned short* __restrict__ Op0, const unsigned short* __restrict__ Op1,
    const unsigned short* __restrict__ Op2, const unsigned short* __restrict__ Op3,
    const float* __restrict__ lp, unsigned short* __restrict__ attnb)
{
    const int row = blockIdx.x;
    const int b = row >> 11, s = row & 2047;
    const int tid = threadIdx.x;
    const int n = tid * 4, h = tid >> 4;
    float lsum = 0.f;
#pragma unroll
    for (int z = 0; z < 4; z++)
        lsum += lp[((size_t)z * 32 + b * 16 + h) * 2048 + s];
    const float inv = 1.f / lsum;
    const size_t off = (size_t)row * 1024 + n;
    ushort4 a0 = *(const ushort4*)&Op0[off];
    ushort4 a1 = *(const ushort4*)&Op1[off];
    ushort4 a2 = *(const ushort4*)&Op2[off];
    ushort4 a3 = *(const ushort4*)&Op3[off];
    ushort4 o;
    o.x = f2bf((bf2f(a0.x) + bf2f(a1.x) + bf2f(a2.x) + bf2f(a3.x)) * inv);
    o.y = f2bf((bf2f(a0.y) + bf2f(a1.y) + bf2f(a2.y) + bf2f(a3.y)) * inv);
    o.z = f2bf((bf2f(a0.z) + bf2f(a1.z) + bf2f(a2.z) + bf2f(a3.z)) * inv);
    o.w = f2bf((bf2f(a0.w) + bf2f(a1.w) + bf2f(a2.w) + bf2f(a3.w)) * inv);
    *(ushort4*)&attnb[off] = o;
}

// ---------------------------------------------------------------------------
// AdaLN (vectorized): x fp32, gamma/beta bf16 (stride 4096, +gboff), out bf16
// ---------------------------------------------------------------------------
__global__ __launch_bounds__(256) void adaln_bf(
    const float* __restrict__ x, const unsigned short* __restrict__ gb, int gboff,
    unsigned short* __restrict__ h)
{
    const int row = blockIdx.x;
    const float* xr = x + (size_t)row * D_MODEL;
    float4 v = ((const float4*)xr)[threadIdx.x];
    float s = v.x + v.y + v.z + v.w;
    float ss = v.x * v.x + v.y * v.y + v.z * v.z + v.w * v.w;
#pragma unroll
    for (int off = 1; off < 64; off <<= 1) {
        s  += __shfl_xor(s, off, 64);
        ss += __shfl_xor(ss, off, 64);
    }
    __shared__ float red[8];
    const int wave = threadIdx.x >> 6;
    if ((threadIdx.x & 63) == 0) { red[wave] = s; red[4 + wave] = ss; }
    __syncthreads();
    s  = red[0] + red[1] + red[2] + red[3];
    ss = red[4] + red[5] + red[6] + red[7];
    const float mu = s * (1.f / 1024.f);
    const float var = ss * (1.f / 1024.f) - mu * mu;
    const float rstd = rsqrtf(var + 1e-5f);
    const int c = threadIdx.x * 4;
    ushort4 g4 = *(const ushort4*)&gb[(size_t)row * 4096 + gboff + c];
    ushort4 b4 = *(const ushort4*)&gb[(size_t)row * 4096 + gboff + 1024 + c];
    ushort4 o;
    o.x = f2bf((v.x - mu) * rstd * (1.f + bf2f(g4.x)) + bf2f(b4.x));
    o.y = f2bf((v.y - mu) * rstd * (1.f + bf2f(g4.y)) + bf2f(b4.y));
    o.z = f2bf((v.z - mu) * rstd * (1.f + bf2f(g4.z)) + bf2f(b4.z));
    o.w = f2bf((v.w - mu) * rstd * (1.f + bf2f(g4.w)) + bf2f(b4.w));
    *(ushort4*)&h[(size_t)row * 1024 + c] = o;
}

// ---------------------------------------------------------------------------
extern "C" void kernel_launch(void* const* d_in, const int* in_sizes, int n_in,
                              void* d_out, int out_size, void* d_ws, size_t ws_size,
                              hipStream_t stream)
{
    const float* x      = (const float*)d_in[0];
    const float* cond   = (const float*)d_in[1];
    const float* p1_w   = (const float*)d_in[2];
    const float* p1_b   = (const float*)d_in[3];
    const float* qkv_w  = (const float*)d_in[4];
    const float* attn_w = (const float*)d_in[5];
    const float* p2_w   = (const float*)d_in[6];
    const float* p2_b   = (const float*)d_in[7];
    const float* ffn_w1 = (const float*)d_in[8];
    const float* ffn_b1 = (const float*)d_in[9];
    const float* ffn_w2 = (const float*)d_in[10];
    const float* ffn_b2 = (const float*)d_in[11];
    float* out = (float*)d_out;

    char* ws = (char*)d_ws;
    const size_t MB = 1024ull * 1024ull;
    unsigned short* wt_cond = (unsigned short*)(ws);             // [0,4)   dead after GB
    unsigned short* wt_qkv  = (unsigned short*)(ws + 4 * MB);    // [4,10)  dead after QKV
    unsigned short* wt_attn = (unsigned short*)(ws + 10 * MB);   // [10,12)
    unsigned short* wt_ffn1 = (unsigned short*)(ws + 12 * MB);   // [12,20)
    unsigned short* wt_ffn2 = (unsigned short*)(ws + 20 * MB);   // [20,28)
    unsigned short* siluc   = (unsigned short*)(ws + 28 * MB);   // [28,32) dead after GB
    unsigned short* gb      = (unsigned short*)(ws + 32 * MB);   // [32,64) dead after adaln#2
    unsigned short* h       = (unsigned short*)(ws + 64 * MB);   // [64,72) h1 dead after QKV
    float*          x1      = (float*)(ws + 72 * MB);            // [72,88) written by PROJ
    unsigned short* qb      = (unsigned short*)(ws + 88 * MB);   // [88,96)
    unsigned short* kb      = (unsigned short*)(ws + 96 * MB);   // [96,104)
    unsigned short* vtb     = (unsigned short*)(ws + 104 * MB);  // [104,112)
    unsigned short* attnb   = (unsigned short*)(ws + 112 * MB);  // [112,120)
    unsigned short* ff1     = (unsigned short*)(ws + 88 * MB);   // [88,120) overlay
    // attention partials, overlaying regions dead at attention time:
    unsigned short* Op0     = (unsigned short*)(ws);             // [0,8)   wt_cond+wt_qkv dead
    unsigned short* Op1     = (unsigned short*)(ws + 64 * MB);   // [64,72) h1 dead
    unsigned short* Op2     = (unsigned short*)(ws + 72 * MB);   // [72,80) x1 written later
    unsigned short* Op3     = (unsigned short*)(ws + 80 * MB);   // [80,88) x1 written later
    float*          lp      = (float*)(ws + 28 * MB);            // [28,29) siluc dead, 1MB
    // FFN2 split-K bf16 partials: gb region dead by FFN2 time. 4 x 8MB = [32,64)
    unsigned short* Pff     = (unsigned short*)(ws + 32 * MB);

    dim3 blk(256);

    // one dispatch: all weight transposes + silu(cond)
    prep_weights<<<dim3(4096), blk, 0, stream>>>(
        p1_w, p2_w, qkv_w, attn_w, ffn_w1, ffn_w2, cond,
        wt_cond, wt_qkv, wt_attn, wt_ffn1, wt_ffn2, siluc);

    // gb = silu(cond) @ [p1_w|p2_w] + [p1_b|p2_b]   (4096x4096, K=512)
    gemm_bf16<EPI_GB, 128><<<dim3(32, 32), blk, 0, stream>>>(
        siluc, wt_cond, p1_b, p2_b, nullptr, gb, nullptr, nullptr, nullptr, 512);
    // h1 = adaln(x, gb1)
    adaln_bf<<<NTOK, blk, 0, stream>>>(x, gb, 0, h);
    // qkv = h1 @ qkv_w  -> q/k bf16 (Q prescaled), v^T bf16 pre-permuted
    gemm_bf16<EPI_QKV, 128><<<dim3(24, 32), blk, 0, stream>>>(
        h, wt_qkv, nullptr, nullptr, nullptr, nullptr, qb, kb, vtb, 1024);
    // attention: split-K x4, 8-wave blocks -> 1024 blocks (4/CU, 32 waves/CU)
    attn_mfma<<<dim3(SEQ / 256, 32, 4), dim3(512), 0, stream>>>(
        qb, kb, vtb, Op0, Op1, Op2, Op3, lp);
    merge_attn<<<dim3(NTOK), blk, 0, stream>>>(Op0, Op1, Op2, Op3, lp, attnb);
    // x1 = x + attn @ attn_out_w   (BM=64 -> 512 blocks)
    gemm_bf16<EPI_PROJ, 64><<<dim3(8, 64), blk, 0, stream>>>(
        attnb, wt_attn, nullptr, nullptr, x, x1, nullptr, nullptr, nullptr, 1024);
    // h2 = adaln(x1, gb2)
    adaln_bf<<<NTOK, blk, 0, stream>>>(x1, gb, 2048, h);
    // ff1 = gelu_tanh(h2 @ ffn_w1 + b1)
    gemm_bf16<EPI_FFN1, 128><<<dim3(32, 32), blk, 0, stream>>>(
        h, wt_ffn1, ffn_b1, nullptr, nullptr, ff1, nullptr, nullptr, nullptr, 1024);
    // FFN2 split-K x4: partials = ff1 @ ffn_w2 (K-slices of 1024), bf16
    // grid (8,64,4) = 2048 blocks -> ~6 blocks/CU (LDS-limited), 24 waves/CU
    gemm_bf16<EPI_PART, 64, 4><<<dim3(8, 64, 4), blk, 0, stream>>>(
        ff1, wt_ffn2, nullptr, nullptr, nullptr, Pff, nullptr, nullptr, nullptr, 4096);
    // out = x1 + b2 + sum_z Pff[z]
    merge_ffn2<<<dim3(4096), blk, 0, stream>>>(Pff, x1, ffn_b2, out);
}

// Round 3
// 385.706 us; speedup vs baseline: 1.0355x; 1.0355x over previous
//
#include <hip/hip_runtime.h>
#include <math.h>

#define D_MODEL 1024
#define SEQ 2048
#define NTOK 4096

typedef __attribute__((ext_vector_type(8))) short bf16x8;
typedef __attribute__((ext_vector_type(4))) float f32x4;

__device__ __forceinline__ unsigned short f2bf(float f) {
    union { float f; unsigned u; } v; v.f = f;
    unsigned r = v.u + 0x7FFFu + ((v.u >> 16) & 1u);   // RNE
    return (unsigned short)(r >> 16);
}
__device__ __forceinline__ float bf2f(unsigned short u) {
    union { unsigned u; float f; } v; v.u = ((unsigned)u) << 16; return v.f;
}
// pack two fp32 -> bf16x2 in one VALU op (RNE). dst.lo = x, dst.hi = y.
__device__ __forceinline__ unsigned cvt_pk_bf16(float x, float y) {
    unsigned r;
    asm("v_cvt_pk_bf16_f32 %0, %1, %2" : "=v"(r) : "v"(x), "v"(y));
    return r;
}

// async global->LDS, 16B per lane. LDS dest must be wave-uniform base + lane*16.
__device__ __forceinline__ void ld_g2l(const void* g, void* l) {
    __builtin_amdgcn_global_load_lds(
        (const __attribute__((address_space(1))) void*)g,
        (__attribute__((address_space(3))) void*)l, 16, 0, 0);
}

// ---------------------------------------------------------------------------
// prep_weights: ONE dispatch does all 6 fp32[K,N]->bf16[N,K] transposes
// plus silu(cond)->bf16.
// ---------------------------------------------------------------------------
__global__ __launch_bounds__(256) void prep_weights(
    const float* __restrict__ p1, const float* __restrict__ p2,
    const float* __restrict__ qkvw, const float* __restrict__ attnw,
    const float* __restrict__ f1, const float* __restrict__ f2,
    const float* __restrict__ cond,
    unsigned short* __restrict__ wt_cond, unsigned short* __restrict__ wt_qkv,
    unsigned short* __restrict__ wt_attn, unsigned short* __restrict__ wt_ffn1,
    unsigned short* __restrict__ wt_ffn2, unsigned short* __restrict__ siluc)
{
    const int t = blockIdx.x;
    if (t >= 3584) {   // silu path: 512 blocks x 1024 float4
        const int base = (t - 3584) * 1024 + threadIdx.x;
#pragma unroll
        for (int i = 0; i < 4; i++) {
            const int idx = base + i * 256;
            float4 v = ((const float4*)cond)[idx];
            ushort4 o;
            o.x = f2bf(v.x / (1.f + expf(-v.x)));
            o.y = f2bf(v.y / (1.f + expf(-v.y)));
            o.z = f2bf(v.z / (1.f + expf(-v.z)));
            o.w = f2bf(v.w / (1.f + expf(-v.w)));
            ((ushort4*)siluc)[idx] = o;
        }
        return;
    }
    const float* src; unsigned short* dst; int K, N, lt;
    if (t < 512)       { src = (t < 256) ? p1 : p2;
                         dst = wt_cond + (t < 256 ? 0 : 2048 * 512);
                         K = 512;  N = 2048; lt = t & 255; }
    else if (t < 1280) { src = qkvw;  dst = wt_qkv;  K = 1024; N = 3072; lt = t - 512; }
    else if (t < 1536) { src = attnw; dst = wt_attn; K = 1024; N = 1024; lt = t - 1280; }
    else if (t < 2560) { src = f1;    dst = wt_ffn1; K = 1024; N = 4096; lt = t - 1536; }
    else               { src = f2;    dst = wt_ffn2; K = 4096; N = 1024; lt = t - 2560; }
    const int ntile = N >> 6;
    const int n0 = (lt % ntile) * 64, k0 = (lt / ntile) * 64;

    __shared__ float tile[64][65];
    const int tx = threadIdx.x & 15, ty = threadIdx.x >> 4;
#pragma unroll
    for (int i = 0; i < 4; i++) {
        const int k = ty + i * 16;
        float4 v = *(const float4*)&src[(size_t)(k0 + k) * N + n0 + tx * 4];
        tile[k][tx * 4 + 0] = v.x; tile[k][tx * 4 + 1] = v.y;
        tile[k][tx * 4 + 2] = v.z; tile[k][tx * 4 + 3] = v.w;
    }
    __syncthreads();
#pragma unroll
    for (int i = 0; i < 4; i++) {
        const int n = ty + i * 16;
        ushort4 o;
        o.x = f2bf(tile[tx * 4 + 0][n]); o.y = f2bf(tile[tx * 4 + 1][n]);
        o.z = f2bf(tile[tx * 4 + 2][n]); o.w = f2bf(tile[tx * 4 + 3][n]);
        *(ushort4*)&dst[(size_t)(n0 + n) * K + k0 + tx * 4] = o;
    }
}

// ---------------------------------------------------------------------------
// bf16 MFMA GEMM: C = epi(A[M,K] @ Bt[N,K]^T). BM x 128 tile, BK=64,
// 4 waves (2x2), 16x16x32 MFMA, global_load_lds staging, XOR swizzle.
// DBUF: double-buffered LDS, single barrier per K-step (T3 2-phase) —
// used for BM=64 instances (grid-limited to 2 blocks/CU; the stall there
// is the per-tile vmcnt(0) drain, which dbuf hides under compute).
// ---------------------------------------------------------------------------
#define EPI_GB   0
#define EPI_QKV  1
#define EPI_PROJ 2
#define EPI_FFN1 3
#define EPI_FFN2 4

template<int EPI, int BM, bool DBUF = false>
__global__ __launch_bounds__(256, 4) void gemm_bf16(
    const unsigned short* __restrict__ A,
    const unsigned short* __restrict__ Bt,
    const float* __restrict__ bias, const float* __restrict__ bias2,
    const float* __restrict__ res,
    void* __restrict__ Cv,
    unsigned short* __restrict__ qb, unsigned short* __restrict__ kb,
    unsigned short* __restrict__ vtb,
    int K)
{
    constexpr int WM = BM / 2;     // 64 or 32
    constexpr int MT = WM / 16;    // 4 or 2
    constexpr int NB = DBUF ? 2 : 1;
    __shared__ __align__(16) unsigned short As[NB][BM * 64];
    __shared__ __align__(16) unsigned short Bs[NB][128 * 64];
    const int tid = threadIdx.x;
    const int lane = tid & 63, w = tid >> 6;
    const int cc = lane & 15, quad = lane >> 4;
    const int wm = (w >> 1) * WM, wn = (w & 1) * 64;
    const int m0 = blockIdx.y * BM, n0 = blockIdx.x * 128;

    f32x4 acc[MT][4];
#pragma unroll
    for (int i = 0; i < MT; i++)
#pragma unroll
        for (int j = 0; j < 4; j++) acc[i][j] = (f32x4)0.f;

    auto stage = [&](int buf, int k0) {
#pragma unroll
        for (int i = 0; i < BM / 32; i++) {
            const int idx = i * 256 + tid;
            const int row = idx >> 3, c = idx & 7;
            const int kc = (c ^ (row & 7)) << 3;
            ld_g2l(&A[(size_t)(m0 + row) * K + k0 + kc], &As[buf][idx << 3]);
        }
#pragma unroll
        for (int i = 0; i < 4; i++) {
            const int idx = i * 256 + tid;
            const int row = idx >> 3, c = idx & 7;
            const int kc = (c ^ (row & 7)) << 3;
            ld_g2l(&Bt[(size_t)(n0 + row) * K + k0 + kc], &Bs[buf][idx << 3]);
        }
    };
    auto compute = [&](int buf) {
#pragma unroll
        for (int ks = 0; ks < 2; ks++) {
            bf16x8 af[MT], bfr[4];
            const int pc = (((ks << 2) | quad) ^ (cc & 7)) << 3;
#pragma unroll
            for (int t = 0; t < MT; t++)
                af[t]  = *(const bf16x8*)&As[buf][(wm + t * 16 + cc) * 64 + pc];
#pragma unroll
            for (int t = 0; t < 4; t++)
                bfr[t] = *(const bf16x8*)&Bs[buf][(wn + t * 16 + cc) * 64 + pc];
#pragma unroll
            for (int mt = 0; mt < MT; mt++)
#pragma unroll
                for (int nt = 0; nt < 4; nt++)
                    acc[mt][nt] = __builtin_amdgcn_mfma_f32_16x16x32_bf16(
                        af[mt], bfr[nt], acc[mt][nt], 0, 0, 0);
        }
    };

    if (DBUF) {
        stage(0, 0);
        int cur = 0;
        for (int k0 = 0; k0 < K; k0 += 64) {
            __syncthreads();            // drains prev stage (vmcnt) + prev reads
            if (k0 + 64 < K) stage(cur ^ 1, k0 + 64);
            compute(cur);
            cur ^= 1;
        }
    } else {
        for (int k0 = 0; k0 < K; k0 += 64) {
            __syncthreads();
            stage(0, k0);
            __syncthreads();
            compute(0);
        }
    }

    // ---- epilogues. C-frag: row = quad*4+r, col = cc ----
    if (EPI == EPI_GB) {
        unsigned short* C = (unsigned short*)Cv;
#pragma unroll
        for (int mt = 0; mt < MT; mt++)
#pragma unroll
        for (int r = 0; r < 4; r++) {
            const int m = m0 + wm + mt * 16 + quad * 4 + r;
#pragma unroll
            for (int nt = 0; nt < 4; nt++) {
                const int n = n0 + wn + nt * 16 + cc;
                const float b = (n < 2048) ? bias[n] : bias2[n - 2048];
                C[(size_t)m * 4096 + n] = f2bf(acc[mt][nt][r] + b);
            }
        }
    } else if (EPI == EPI_PROJ) {
        float* C = (float*)Cv;
#pragma unroll
        for (int mt = 0; mt < MT; mt++)
#pragma unroll
        for (int r = 0; r < 4; r++) {
            const int m = m0 + wm + mt * 16 + quad * 4 + r;
#pragma unroll
            for (int nt = 0; nt < 4; nt++) {
                const int n = n0 + wn + nt * 16 + cc;
                C[(size_t)m * 1024 + n] = acc[mt][nt][r] + res[(size_t)m * 1024 + n];
            }
        }
    } else if (EPI == EPI_FFN1) {
        unsigned short* C = (unsigned short*)Cv;
#pragma unroll
        for (int mt = 0; mt < MT; mt++)
#pragma unroll
        for (int r = 0; r < 4; r++) {
            const int m = m0 + wm + mt * 16 + quad * 4 + r;
#pragma unroll
            for (int nt = 0; nt < 4; nt++) {
                const int n = n0 + wn + nt * 16 + cc;
                float v = acc[mt][nt][r] + bias[n];
                // tanh-approx GELU: x / (1 + exp2(-2.3022084*(x + 0.044715 x^3)))
                const float u = v + 0.044715f * v * v * v;
                const float g = v / (1.f + exp2f(-2.3022084f * u));
                C[(size_t)m * 4096 + n] = f2bf(g);
            }
        }
    } else if (EPI == EPI_FFN2) {
        float* C = (float*)Cv;
#pragma unroll
        for (int mt = 0; mt < MT; mt++)
#pragma unroll
        for (int r = 0; r < 4; r++) {
            const int m = m0 + wm + mt * 16 + quad * 4 + r;
#pragma unroll
            for (int nt = 0; nt < 4; nt++) {
                const int n = n0 + wn + nt * 16 + cc;
                C[(size_t)m * 1024 + n] = acc[mt][nt][r] + bias[n] + res[(size_t)m * 1024 + n];
            }
        }
    } else {  // EPI_QKV: N=3072, split q/k bf16 + PERMUTED v^T bf16
        const int region = n0 >> 10;
        const int b = m0 >> 11;
        if (region < 2) {
            unsigned short* dst = region ? kb : qb;
            // Q prescale folds softmax 1/sqrt(d) AND log2(e)
            const float sc = region ? 1.0f : 0.125f * 1.44269504088896340736f;
#pragma unroll
            for (int mt = 0; mt < MT; mt++)
#pragma unroll
            for (int r = 0; r < 4; r++) {
                const int m = m0 + wm + mt * 16 + quad * 4 + r;
                const int s = m & 2047;
#pragma unroll
                for (int nt = 0; nt < 4; nt++) {
                    const int n = (n0 + wn + nt * 16 + cc) & 1023;
                    const int hh = n >> 6, d = n & 63;
                    dst[(((size_t)b * 16 + hh) * 2048 + s) * 64 + d] =
                        f2bf(acc[mt][nt][r] * sc);
                }
            }
        } else {
            // V^T stored pre-permuted into PV B-fragment key order
            const int sb = (m0 + wm) & 2047;
#pragma unroll
            for (int mt = 0; mt < MT; mt++) {
                const int kpos = sb + ((mt >> 1) << 5) + (quad << 3) + ((mt & 1) << 2);
#pragma unroll
                for (int nt = 0; nt < 4; nt++) {
                    const int n = (n0 + wn + nt * 16 + cc) & 1023;
                    const int hh = n >> 6, d = n & 63;
                    ushort4 o;
                    o.x = f2bf(acc[mt][nt][0]); o.y = f2bf(acc[mt][nt][1]);
                    o.z = f2bf(acc[mt][nt][2]); o.w = f2bf(acc[mt][nt][3]);
                    *(ushort4*)&vtb[(((size_t)b * 16 + hh) * 64 + d) * 2048 + kpos] = o;
                }
            }
        }
    }
}

// ---------------------------------------------------------------------------
// Transposed MFMA flash attention, split-K x4, double-buffered K/V LDS
// (one barrier per 64-key tile; next tile's global_load_lds issued before
// compute so the load latency hides under QK^T/softmax/PV).
// Static-max exp2 softmax; P->bf16 via v_cvt_pk_bf16_f32; l via all-ones-A
// MFMA; S^T zero-init folded into the first kh MFMA (C = persistent zero).
// ---------------------------------------------------------------------------
__global__ __launch_bounds__(512, 4) void attn_mfma(
    const unsigned short* __restrict__ qb, const unsigned short* __restrict__ kb,
    const unsigned short* __restrict__ vtb,
    unsigned short* __restrict__ Op0, unsigned short* __restrict__ Op1,
    unsigned short* __restrict__ Op2, unsigned short* __restrict__ Op3,
    float* __restrict__ lp)
{
    __shared__ __align__(16) unsigned short ks[2][64 * 64];   // [key][d] swizzled
    __shared__ __align__(16) unsigned short vts[2][64 * 64];  // [d][pos] swizzled

    const int tid = threadIdx.x;
    const int lane = tid & 63, w = tid >> 6;           // 8 waves
    const int c = lane & 15, quad = lane >> 4;
    const int bh = blockIdx.y;
    const int q0 = blockIdx.x * 256;
    const int z = blockIdx.z;
    const int kk0 = z * 512;

    // Q as B-operand: lane needs Q[q0+w*32+qs*16+c][kh*32+quad*8+j]
    bf16x8 qf[2][2];   // [qs][kh]
#pragma unroll
    for (int qs = 0; qs < 2; qs++) {
        const size_t base = (((size_t)bh * 2048) + q0 + w * 32 + qs * 16 + c) * 64 + quad * 8;
        qf[qs][0] = *(const bf16x8*)&qb[base];
        qf[qs][1] = *(const bf16x8*)&qb[base + 32];
    }

    // all-ones bf16 A-operand for the l (row-sum) MFMA; persistent zero C
    bf16x8 ones;
#pragma unroll
    for (int i = 0; i < 8; i++) ones[i] = (short)0x3F80;
    const f32x4 fz = (f32x4)0.f;

    f32x4 of[2][4];
#pragma unroll
    for (int qs = 0; qs < 2; qs++)
#pragma unroll
        for (int i = 0; i < 4; i++) of[qs][i] = (f32x4)0.f;
    f32x4 lf[2];
    lf[0] = (f32x4)0.f; lf[1] = (f32x4)0.f;

    const size_t kbase = ((size_t)bh * 2048) * 64;
    const size_t vbase = ((size_t)bh * 64) * 2048;

    // stage addressing: 512 chunks of 16B per tile, one per thread
    const int srow = tid >> 3, spc = tid & 7;
    const int slc = spc ^ (srow & 7);

    auto stage = [&](int buf, int kk) {
        ld_g2l(&kb[kbase + (size_t)(kk + srow) * 64 + slc * 8], &ks[buf][tid << 3]);
        ld_g2l(&vtb[vbase + (size_t)srow * 2048 + kk + slc * 8], &vts[buf][tid << 3]);
    };

    stage(0, kk0);
    int cur = 0;
    for (int kk = kk0; kk < kk0 + 512; kk += 64) {
        __syncthreads();                     // buf[cur] staged; prev reads done
        if (kk + 64 < kk0 + 512) stage(cur ^ 1, kk + 64);

        // ---- S^T = K @ Q^T (first kh writes into zero-C, no v_mov init) ----
        f32x4 sc[2][4];
#pragma unroll
        for (int t = 0; t < 4; t++) {
            const int phys0 = ((0 * 4 + quad) ^ (c & 7)) << 3;
            const int phys1 = ((1 * 4 + quad) ^ (c & 7)) << 3;
            bf16x8 kf0 = *(const bf16x8*)&ks[cur][(t * 16 + c) * 64 + phys0];
            sc[0][t] = __builtin_amdgcn_mfma_f32_16x16x32_bf16(kf0, qf[0][0], fz, 0, 0, 0);
            sc[1][t] = __builtin_amdgcn_mfma_f32_16x16x32_bf16(kf0, qf[1][0], fz, 0, 0, 0);
            bf16x8 kf1 = *(const bf16x8*)&ks[cur][(t * 16 + c) * 64 + phys1];
            sc[0][t] = __builtin_amdgcn_mfma_f32_16x16x32_bf16(kf1, qf[0][1], sc[0][t], 0, 0, 0);
            sc[1][t] = __builtin_amdgcn_mfma_f32_16x16x32_bf16(kf1, qf[1][1], sc[1][t], 0, 0, 0);
        }

        // ---- softmax: static max, exp2 domain; pack via v_cvt_pk_bf16_f32 ----
        bf16x8 pb[2][2];
#pragma unroll
        for (int qs = 0; qs < 2; qs++) {
#pragma unroll
            for (int t = 0; t < 4; t++)
#pragma unroll
                for (int r = 0; r < 4; r++)
                    sc[qs][t][r] = exp2f(sc[qs][t][r]);
#pragma unroll
            for (int kh = 0; kh < 2; kh++) {
                union { int4 i; bf16x8 v; } u;
                u.i.x = cvt_pk_bf16(sc[qs][2 * kh][0],     sc[qs][2 * kh][1]);
                u.i.y = cvt_pk_bf16(sc[qs][2 * kh][2],     sc[qs][2 * kh][3]);
                u.i.z = cvt_pk_bf16(sc[qs][2 * kh + 1][0], sc[qs][2 * kh + 1][1]);
                u.i.w = cvt_pk_bf16(sc[qs][2 * kh + 1][2], sc[qs][2 * kh + 1][3]);
                pb[qs][kh] = u.v;
            }
        }

        // ---- l[q] on the matrix pipe: ones(16x32) @ P^T -> every row = colsum ----
#pragma unroll
        for (int qs = 0; qs < 2; qs++)
#pragma unroll
            for (int kh = 0; kh < 2; kh++)
                lf[qs] = __builtin_amdgcn_mfma_f32_16x16x32_bf16(
                    ones, pb[qs][kh], lf[qs], 0, 0, 0);

        // ---- O^T += V^T @ P^T ----
#pragma unroll
        for (int dt = 0; dt < 4; dt++) {
#pragma unroll
            for (int kh = 0; kh < 2; kh++) {
                const int phys = ((kh * 4 + quad) ^ (c & 7)) << 3;
                bf16x8 vf = *(const bf16x8*)&vts[cur][(dt * 16 + c) * 64 + phys];
#pragma unroll
                for (int qs = 0; qs < 2; qs++)
                    of[qs][dt] = __builtin_amdgcn_mfma_f32_16x16x32_bf16(
                        vf, pb[qs][kh], of[qs][dt], 0, 0, 0);
            }
        }
        cur ^= 1;
    }

    // ---- epilogue: store UNSCALED partial O (bf16) + partial l ----
    unsigned short* Op = (z == 0) ? Op0 : (z == 1) ? Op1 : (z == 2) ? Op2 : Op3;
    const int b = bh >> 4, hh = bh & 15;
#pragma unroll
    for (int qs = 0; qs < 2; qs++) {
        const int q = q0 + w * 32 + qs * 16 + c;
        if (lane < 16)
            lp[((size_t)z * 32 + bh) * 2048 + q] = lf[qs][0];
        const size_t row = (size_t)(b * 2048 + q);
#pragma unroll
        for (int dt = 0; dt < 4; dt++) {
            ushort4 o;
            o.x = f2bf(of[qs][dt][0]); o.y = f2bf(of[qs][dt][1]);
            o.z = f2bf(of[qs][dt][2]); o.w = f2bf(of[qs][dt][3]);
            *(ushort4*)&Op[row * 1024 + hh * 64 + dt * 16 + quad * 4] = o;
        }
    }
}

// ---------------------------------------------------------------------------
// merge_attn: attnb = (Op0+Op1+Op2+Op3) / (l0+l1+l2+l3), bf16 out.
// ---------------------------------------------------------------------------
__global__ __launch_bounds__(256) void merge_attn(
    const unsigned short* __restrict__ Op0, const unsigned short* __restrict__ Op1,
    const unsigned short* __restrict__ Op2, const unsigned short* __restrict__ Op3,
    const float* __restrict__ lp, unsigned short* __restrict__ attnb)
{
    const int row = blockIdx.x;
    const int b = row >> 11, s = row & 2047;
    const int tid = threadIdx.x;
    const int n = tid * 4, h = tid >> 4;
    float lsum = 0.f;
#pragma unroll
    for (int z = 0; z < 4; z++)
        lsum += lp[((size_t)z * 32 + b * 16 + h) * 2048 + s];
    const float inv = 1.f / lsum;
    const size_t off = (size_t)row * 1024 + n;
    ushort4 a0 = *(const ushort4*)&Op0[off];
    ushort4 a1 = *(const ushort4*)&Op1[off];
    ushort4 a2 = *(const ushort4*)&Op2[off];
    ushort4 a3 = *(const ushort4*)&Op3[off];
    ushort4 o;
    o.x = f2bf((bf2f(a0.x) + bf2f(a1.x) + bf2f(a2.x) + bf2f(a3.x)) * inv);
    o.y = f2bf((bf2f(a0.y) + bf2f(a1.y) + bf2f(a2.y) + bf2f(a3.y)) * inv);
    o.z = f2bf((bf2f(a0.z) + bf2f(a1.z) + bf2f(a2.z) + bf2f(a3.z)) * inv);
    o.w = f2bf((bf2f(a0.w) + bf2f(a1.w) + bf2f(a2.w) + bf2f(a3.w)) * inv);
    *(ushort4*)&attnb[off] = o;
}

// ---------------------------------------------------------------------------
// AdaLN (vectorized): x fp32, gamma/beta bf16 (stride 4096, +gboff), out bf16
// ---------------------------------------------------------------------------
__global__ __launch_bounds__(256) void adaln_bf(
    const float* __restrict__ x, const unsigned short* __restrict__ gb, int gboff,
    unsigned short* __restrict__ h)
{
    const int row = blockIdx.x;
    const float* xr = x + (size_t)row * D_MODEL;
    float4 v = ((const float4*)xr)[threadIdx.x];
    float s = v.x + v.y + v.z + v.w;
    float ss = v.x * v.x + v.y * v.y + v.z * v.z + v.w * v.w;
#pragma unroll
    for (int off = 1; off < 64; off <<= 1) {
        s  += __shfl_xor(s, off, 64);
        ss += __shfl_xor(ss, off, 64);
    }
    __shared__ float red[8];
    const int wave = threadIdx.x >> 6;
    if ((threadIdx.x & 63) == 0) { red[wave] = s; red[4 + wave] = ss; }
    __syncthreads();
    s  = red[0] + red[1] + red[2] + red[3];
    ss = red[4] + red[5] + red[6] + red[7];
    const float mu = s * (1.f / 1024.f);
    const float var = ss * (1.f / 1024.f) - mu * mu;
    const float rstd = rsqrtf(var + 1e-5f);
    const int c = threadIdx.x * 4;
    ushort4 g4 = *(const ushort4*)&gb[(size_t)row * 4096 + gboff + c];
    ushort4 b4 = *(const ushort4*)&gb[(size_t)row * 4096 + gboff + 1024 + c];
    ushort4 o;
    o.x = f2bf((v.x - mu) * rstd * (1.f + bf2f(g4.x)) + bf2f(b4.x));
    o.y = f2bf((v.y - mu) * rstd * (1.f + bf2f(g4.y)) + bf2f(b4.y));
    o.z = f2bf((v.z - mu) * rstd * (1.f + bf2f(g4.z)) + bf2f(b4.z));
    o.w = f2bf((v.w - mu) * rstd * (1.f + bf2f(g4.w)) + bf2f(b4.w));
    *(ushort4*)&h[(size_t)row * 1024 + c] = o;
}

// ---------------------------------------------------------------------------
extern "C" void kernel_launch(void* const* d_in, const int* in_sizes, int n_in,
                              void* d_out, int out_size, void* d_ws, size_t ws_size,
                              hipStream_t stream)
{
    const float* x      = (const float*)d_in[0];
    const float* cond   = (const float*)d_in[1];
    const float* p1_w   = (const float*)d_in[2];
    const float* p1_b   = (const float*)d_in[3];
    const float* qkv_w  = (const float*)d_in[4];
    const float* attn_w = (const float*)d_in[5];
    const float* p2_w   = (const float*)d_in[6];
    const float* p2_b   = (const float*)d_in[7];
    const float* ffn_w1 = (const float*)d_in[8];
    const float* ffn_b1 = (const float*)d_in[9];
    const float* ffn_w2 = (const float*)d_in[10];
    const float* ffn_b2 = (const float*)d_in[11];
    float* out = (float*)d_out;

    char* ws = (char*)d_ws;
    const size_t MB = 1024ull * 1024ull;
    unsigned short* wt_cond = (unsigned short*)(ws);             // [0,4)   dead after GB
    unsigned short* wt_qkv  = (unsigned short*)(ws + 4 * MB);    // [4,10)  dead after QKV
    unsigned short* wt_attn = (unsigned short*)(ws + 10 * MB);   // [10,12)
    unsigned short* wt_ffn1 = (unsigned short*)(ws + 12 * MB);   // [12,20)
    unsigned short* wt_ffn2 = (unsigned short*)(ws + 20 * MB);   // [20,28)
    unsigned short* siluc   = (unsigned short*)(ws + 28 * MB);   // [28,32) dead after GB
    unsigned short* gb      = (unsigned short*)(ws + 32 * MB);   // [32,64)
    unsigned short* h       = (unsigned short*)(ws + 64 * MB);   // [64,72) h1 dead after QKV
    float*          x1      = (float*)(ws + 72 * MB);            // [72,88) written by PROJ
    unsigned short* qb      = (unsigned short*)(ws + 88 * MB);   // [88,96)
    unsigned short* kb      = (unsigned short*)(ws + 96 * MB);   // [96,104)
    unsigned short* vtb     = (unsigned short*)(ws + 104 * MB);  // [104,112)
    unsigned short* attnb   = (unsigned short*)(ws + 112 * MB);  // [112,120)
    unsigned short* ff1     = (unsigned short*)(ws + 88 * MB);   // [88,120) overlay
    // attention partials, overlaying regions dead at attention time:
    unsigned short* Op0     = (unsigned short*)(ws);             // [0,8)   wt_cond+wt_qkv dead
    unsigned short* Op1     = (unsigned short*)(ws + 64 * MB);   // [64,72) h1 dead
    unsigned short* Op2     = (unsigned short*)(ws + 72 * MB);   // [72,80) x1 written later
    unsigned short* Op3     = (unsigned short*)(ws + 80 * MB);   // [80,88) x1 written later
    float*          lp      = (float*)(ws + 28 * MB);            // [28,29) siluc dead, 1MB

    dim3 blk(256);

    // one dispatch: all weight transposes + silu(cond)
    prep_weights<<<dim3(4096), blk, 0, stream>>>(
        p1_w, p2_w, qkv_w, attn_w, ffn_w1, ffn_w2, cond,
        wt_cond, wt_qkv, wt_attn, wt_ffn1, wt_ffn2, siluc);

    // gb = silu(cond) @ [p1_w|p2_w] + [p1_b|p2_b]   (4096x4096, K=512)
    gemm_bf16<EPI_GB, 128><<<dim3(32, 32), blk, 0, stream>>>(
        siluc, wt_cond, p1_b, p2_b, nullptr, gb, nullptr, nullptr, nullptr, 512);
    // h1 = adaln(x, gb1)
    adaln_bf<<<NTOK, blk, 0, stream>>>(x, gb, 0, h);
    // qkv = h1 @ qkv_w  -> q/k bf16 (Q prescaled), v^T bf16 pre-permuted
    gemm_bf16<EPI_QKV, 128><<<dim3(24, 32), blk, 0, stream>>>(
        h, wt_qkv, nullptr, nullptr, nullptr, nullptr, qb, kb, vtb, 1024);
    // attention: split-K x4, 8-wave blocks -> 1024 blocks
    attn_mfma<<<dim3(SEQ / 256, 32, 4), dim3(512), 0, stream>>>(
        qb, kb, vtb, Op0, Op1, Op2, Op3, lp);
    merge_attn<<<dim3(NTOK), blk, 0, stream>>>(Op0, Op1, Op2, Op3, lp, attnb);
    // x1 = x + attn @ attn_out_w   (BM=64 dbuf -> 512 blocks)
    gemm_bf16<EPI_PROJ, 64, true><<<dim3(8, 64), blk, 0, stream>>>(
        attnb, wt_attn, nullptr, nullptr, x, x1, nullptr, nullptr, nullptr, 1024);
    // h2 = adaln(x1, gb2)
    adaln_bf<<<NTOK, blk, 0, stream>>>(x1, gb, 2048, h);
    // ff1 = gelu_tanh(h2 @ ffn_w1 + b1)
    gemm_bf16<EPI_FFN1, 128><<<dim3(32, 32), blk, 0, stream>>>(
        h, wt_ffn1, ffn_b1, nullptr, nullptr, ff1, nullptr, nullptr, nullptr, 1024);
    // out = x1 + ff1 @ ffn_w2 + b2   (BM=64 dbuf -> 512 blocks)
    gemm_bf16<EPI_FFN2, 64, true><<<dim3(8, 64), blk, 0, stream>>>(
        ff1, wt_ffn2, ffn_b2, nullptr, x1, out, nullptr, nullptr, nullptr, 4096);
}

// Round 4
// 382.945 us; speedup vs baseline: 1.0429x; 1.0072x over previous
//
#include <hip/hip_runtime.h>
#include <math.h>

#define D_MODEL 1024
#define SEQ 2048
#define NTOK 4096

typedef __attribute__((ext_vector_type(8))) short bf16x8;
typedef __attribute__((ext_vector_type(4))) float f32x4;

__device__ __forceinline__ unsigned short f2bf(float f) {
    union { float f; unsigned u; } v; v.f = f;
    unsigned r = v.u + 0x7FFFu + ((v.u >> 16) & 1u);   // RNE
    return (unsigned short)(r >> 16);
}
__device__ __forceinline__ float bf2f(unsigned short u) {
    union { unsigned u; float f; } v; v.u = ((unsigned)u) << 16; return v.f;
}
// pack two fp32 -> bf16x2 in one VALU op (RNE). dst.lo = x, dst.hi = y.
__device__ __forceinline__ unsigned cvt_pk_bf16(float x, float y) {
    unsigned r;
    asm("v_cvt_pk_bf16_f32 %0, %1, %2" : "=v"(r) : "v"(x), "v"(y));
    return r;
}

// async global->LDS, 16B per lane. LDS dest must be wave-uniform base + lane*16.
__device__ __forceinline__ void ld_g2l(const void* g, void* l) {
    __builtin_amdgcn_global_load_lds(
        (const __attribute__((address_space(1))) void*)g,
        (__attribute__((address_space(3))) void*)l, 16, 0, 0);
}

// ---------------------------------------------------------------------------
// prep_weights: ONE dispatch does all 6 fp32[K,N]->bf16[N,K] transposes
// plus silu(cond)->bf16.
// ---------------------------------------------------------------------------
__global__ __launch_bounds__(256) void prep_weights(
    const float* __restrict__ p1, const float* __restrict__ p2,
    const float* __restrict__ qkvw, const float* __restrict__ attnw,
    const float* __restrict__ f1, const float* __restrict__ f2,
    const float* __restrict__ cond,
    unsigned short* __restrict__ wt_cond, unsigned short* __restrict__ wt_qkv,
    unsigned short* __restrict__ wt_attn, unsigned short* __restrict__ wt_ffn1,
    unsigned short* __restrict__ wt_ffn2, unsigned short* __restrict__ siluc)
{
    const int t = blockIdx.x;
    if (t >= 3584) {   // silu path: 512 blocks x 1024 float4
        const int base = (t - 3584) * 1024 + threadIdx.x;
#pragma unroll
        for (int i = 0; i < 4; i++) {
            const int idx = base + i * 256;
            float4 v = ((const float4*)cond)[idx];
            ushort4 o;
            o.x = f2bf(v.x / (1.f + expf(-v.x)));
            o.y = f2bf(v.y / (1.f + expf(-v.y)));
            o.z = f2bf(v.z / (1.f + expf(-v.z)));
            o.w = f2bf(v.w / (1.f + expf(-v.w)));
            ((ushort4*)siluc)[idx] = o;
        }
        return;
    }
    const float* src; unsigned short* dst; int K, N, lt;
    if (t < 512)       { src = (t < 256) ? p1 : p2;
                         dst = wt_cond + (t < 256 ? 0 : 2048 * 512);
                         K = 512;  N = 2048; lt = t & 255; }
    else if (t < 1280) { src = qkvw;  dst = wt_qkv;  K = 1024; N = 3072; lt = t - 512; }
    else if (t < 1536) { src = attnw; dst = wt_attn; K = 1024; N = 1024; lt = t - 1280; }
    else if (t < 2560) { src = f1;    dst = wt_ffn1; K = 1024; N = 4096; lt = t - 1536; }
    else               { src = f2;    dst = wt_ffn2; K = 4096; N = 1024; lt = t - 2560; }
    const int ntile = N >> 6;
    const int n0 = (lt % ntile) * 64, k0 = (lt / ntile) * 64;

    __shared__ float tile[64][65];
    const int tx = threadIdx.x & 15, ty = threadIdx.x >> 4;
#pragma unroll
    for (int i = 0; i < 4; i++) {
        const int k = ty + i * 16;
        float4 v = *(const float4*)&src[(size_t)(k0 + k) * N + n0 + tx * 4];
        tile[k][tx * 4 + 0] = v.x; tile[k][tx * 4 + 1] = v.y;
        tile[k][tx * 4 + 2] = v.z; tile[k][tx * 4 + 3] = v.w;
    }
    __syncthreads();
#pragma unroll
    for (int i = 0; i < 4; i++) {
        const int n = ty + i * 16;
        ushort4 o;
        o.x = f2bf(tile[tx * 4 + 0][n]); o.y = f2bf(tile[tx * 4 + 1][n]);
        o.z = f2bf(tile[tx * 4 + 2][n]); o.w = f2bf(tile[tx * 4 + 3][n]);
        *(ushort4*)&dst[(size_t)(n0 + n) * K + k0 + tx * 4] = o;
    }
}

// ---------------------------------------------------------------------------
// bf16 MFMA GEMM: C = epi(A[M,K] @ Bt[N,K]^T). BM x 128 tile, BK=64,
// 4 waves (2x2), 16x16x32 MFMA, global_load_lds staging, XOR swizzle.
// DBUF: double-buffered LDS, single barrier per K-step.
// SPLIT>1: grid.z splits K; EPI_PART writes bf16 partials (merge_ffn2 sums).
// ---------------------------------------------------------------------------
#define EPI_GB   0
#define EPI_QKV  1
#define EPI_PROJ 2
#define EPI_FFN1 3
#define EPI_FFN2 4
#define EPI_PART 5

template<int EPI, int BM, bool DBUF = false, int SPLIT = 1>
__global__ __launch_bounds__(256, 4) void gemm_bf16(
    const unsigned short* __restrict__ A,
    const unsigned short* __restrict__ Bt,
    const float* __restrict__ bias, const float* __restrict__ bias2,
    const float* __restrict__ res,
    void* __restrict__ Cv,
    unsigned short* __restrict__ qb, unsigned short* __restrict__ kb,
    unsigned short* __restrict__ vtb,
    int K)
{
    constexpr int WM = BM / 2;     // 64 or 32
    constexpr int MT = WM / 16;    // 4 or 2
    constexpr int NB = DBUF ? 2 : 1;
    __shared__ __align__(16) unsigned short As[NB][BM * 64];
    __shared__ __align__(16) unsigned short Bs[NB][128 * 64];
    const int tid = threadIdx.x;
    const int lane = tid & 63, w = tid >> 6;
    const int cc = lane & 15, quad = lane >> 4;
    const int wm = (w >> 1) * WM, wn = (w & 1) * 64;
    const int m0 = blockIdx.y * BM, n0 = blockIdx.x * 128;
    const int kslice = K / SPLIT;
    const int kbeg = (SPLIT > 1) ? (int)blockIdx.z * kslice : 0;

    f32x4 acc[MT][4];
#pragma unroll
    for (int i = 0; i < MT; i++)
#pragma unroll
        for (int j = 0; j < 4; j++) acc[i][j] = (f32x4)0.f;

    auto stage = [&](int buf, int k0) {
#pragma unroll
        for (int i = 0; i < BM / 32; i++) {
            const int idx = i * 256 + tid;
            const int row = idx >> 3, c = idx & 7;
            const int kc = (c ^ (row & 7)) << 3;
            ld_g2l(&A[(size_t)(m0 + row) * K + k0 + kc], &As[buf][idx << 3]);
        }
#pragma unroll
        for (int i = 0; i < 4; i++) {
            const int idx = i * 256 + tid;
            const int row = idx >> 3, c = idx & 7;
            const int kc = (c ^ (row & 7)) << 3;
            ld_g2l(&Bt[(size_t)(n0 + row) * K + k0 + kc], &Bs[buf][idx << 3]);
        }
    };
    auto compute = [&](int buf) {
#pragma unroll
        for (int ks = 0; ks < 2; ks++) {
            bf16x8 af[MT], bfr[4];
            const int pc = (((ks << 2) | quad) ^ (cc & 7)) << 3;
#pragma unroll
            for (int t = 0; t < MT; t++)
                af[t]  = *(const bf16x8*)&As[buf][(wm + t * 16 + cc) * 64 + pc];
#pragma unroll
            for (int t = 0; t < 4; t++)
                bfr[t] = *(const bf16x8*)&Bs[buf][(wn + t * 16 + cc) * 64 + pc];
#pragma unroll
            for (int mt = 0; mt < MT; mt++)
#pragma unroll
                for (int nt = 0; nt < 4; nt++)
                    acc[mt][nt] = __builtin_amdgcn_mfma_f32_16x16x32_bf16(
                        af[mt], bfr[nt], acc[mt][nt], 0, 0, 0);
        }
    };

    if (DBUF) {
        stage(0, kbeg);
        int cur = 0;
        for (int k0 = kbeg; k0 < kbeg + kslice; k0 += 64) {
            __syncthreads();            // drains this buf's stage + prev reads
            if (k0 + 64 < kbeg + kslice) stage(cur ^ 1, k0 + 64);
            compute(cur);
            cur ^= 1;
        }
    } else {
        for (int k0 = kbeg; k0 < kbeg + kslice; k0 += 64) {
            __syncthreads();
            stage(0, k0);
            __syncthreads();
            compute(0);
        }
    }

    // ---- epilogues. C-frag: row = quad*4+r, col = cc ----
    if (EPI == EPI_GB) {
        unsigned short* C = (unsigned short*)Cv;
#pragma unroll
        for (int mt = 0; mt < MT; mt++)
#pragma unroll
        for (int r = 0; r < 4; r++) {
            const int m = m0 + wm + mt * 16 + quad * 4 + r;
#pragma unroll
            for (int nt = 0; nt < 4; nt++) {
                const int n = n0 + wn + nt * 16 + cc;
                const float b = (n < 2048) ? bias[n] : bias2[n - 2048];
                C[(size_t)m * 4096 + n] = f2bf(acc[mt][nt][r] + b);
            }
        }
    } else if (EPI == EPI_PROJ) {
        float* C = (float*)Cv;
#pragma unroll
        for (int mt = 0; mt < MT; mt++)
#pragma unroll
        for (int r = 0; r < 4; r++) {
            const int m = m0 + wm + mt * 16 + quad * 4 + r;
#pragma unroll
            for (int nt = 0; nt < 4; nt++) {
                const int n = n0 + wn + nt * 16 + cc;
                C[(size_t)m * 1024 + n] = acc[mt][nt][r] + res[(size_t)m * 1024 + n];
            }
        }
    } else if (EPI == EPI_FFN1) {
        unsigned short* C = (unsigned short*)Cv;
#pragma unroll
        for (int mt = 0; mt < MT; mt++)
#pragma unroll
        for (int r = 0; r < 4; r++) {
            const int m = m0 + wm + mt * 16 + quad * 4 + r;
#pragma unroll
            for (int nt = 0; nt < 4; nt++) {
                const int n = n0 + wn + nt * 16 + cc;
                float v = acc[mt][nt][r] + bias[n];
                // tanh-approx GELU: x / (1 + exp2(-2.3022084*(x + 0.044715 x^3)))
                const float u = v + 0.044715f * v * v * v;
                const float g = v / (1.f + exp2f(-2.3022084f * u));
                C[(size_t)m * 4096 + n] = f2bf(g);
            }
        }
    } else if (EPI == EPI_PART) {
        // bf16 partial: Cv + z * M*1024
        unsigned short* C = (unsigned short*)Cv + (size_t)blockIdx.z * (4096ull * 1024ull);
#pragma unroll
        for (int mt = 0; mt < MT; mt++)
#pragma unroll
        for (int r = 0; r < 4; r++) {
            const int m = m0 + wm + mt * 16 + quad * 4 + r;
#pragma unroll
            for (int nt = 0; nt < 4; nt++) {
                const int n = n0 + wn + nt * 16 + cc;
                C[(size_t)m * 1024 + n] = f2bf(acc[mt][nt][r]);
            }
        }
    } else if (EPI == EPI_FFN2) {
        float* C = (float*)Cv;
#pragma unroll
        for (int mt = 0; mt < MT; mt++)
#pragma unroll
        for (int r = 0; r < 4; r++) {
            const int m = m0 + wm + mt * 16 + quad * 4 + r;
#pragma unroll
            for (int nt = 0; nt < 4; nt++) {
                const int n = n0 + wn + nt * 16 + cc;
                C[(size_t)m * 1024 + n] = acc[mt][nt][r] + bias[n] + res[(size_t)m * 1024 + n];
            }
        }
    } else {  // EPI_QKV: N=3072, split q/k bf16 + PERMUTED v^T bf16
        const int region = n0 >> 10;
        const int b = m0 >> 11;
        if (region < 2) {
            unsigned short* dst = region ? kb : qb;
            // Q prescale folds softmax 1/sqrt(d) AND log2(e)
            const float sc = region ? 1.0f : 0.125f * 1.44269504088896340736f;
#pragma unroll
            for (int mt = 0; mt < MT; mt++)
#pragma unroll
            for (int r = 0; r < 4; r++) {
                const int m = m0 + wm + mt * 16 + quad * 4 + r;
                const int s = m & 2047;
#pragma unroll
                for (int nt = 0; nt < 4; nt++) {
                    const int n = (n0 + wn + nt * 16 + cc) & 1023;
                    const int hh = n >> 6, d = n & 63;
                    dst[(((size_t)b * 16 + hh) * 2048 + s) * 64 + d] =
                        f2bf(acc[mt][nt][r] * sc);
                }
            }
        } else {
            // V^T stored pre-permuted into PV B-fragment key order
            const int sb = (m0 + wm) & 2047;
#pragma unroll
            for (int mt = 0; mt < MT; mt++) {
                const int kpos = sb + ((mt >> 1) << 5) + (quad << 3) + ((mt & 1) << 2);
#pragma unroll
                for (int nt = 0; nt < 4; nt++) {
                    const int n = (n0 + wn + nt * 16 + cc) & 1023;
                    const int hh = n >> 6, d = n & 63;
                    ushort4 o;
                    o.x = f2bf(acc[mt][nt][0]); o.y = f2bf(acc[mt][nt][1]);
                    o.z = f2bf(acc[mt][nt][2]); o.w = f2bf(acc[mt][nt][3]);
                    *(ushort4*)&vtb[(((size_t)b * 16 + hh) * 64 + d) * 2048 + kpos] = o;
                }
            }
        }
    }
}

// ---------------------------------------------------------------------------
// merge_ffn2: out = x1 + b2 + sum_z P[z]   (P bf16 partials x2, out fp32)
// ---------------------------------------------------------------------------
__global__ __launch_bounds__(256) void merge_ffn2(
    const unsigned short* __restrict__ P, const float* __restrict__ x1,
    const float* __restrict__ b2, float* __restrict__ out)
{
    const size_t idx = (size_t)blockIdx.x * 1024 + (size_t)threadIdx.x * 4;
    const int n = (int)(idx & 1023);
    float4 xv = *(const float4*)&x1[idx];
    float4 bv = *(const float4*)&b2[n];
    ushort4 p0 = *(const ushort4*)&P[idx];
    ushort4 p1 = *(const ushort4*)&P[(4096ull * 1024ull) + idx];
    float4 o;
    o.x = xv.x + bv.x + bf2f(p0.x) + bf2f(p1.x);
    o.y = xv.y + bv.y + bf2f(p0.y) + bf2f(p1.y);
    o.z = xv.z + bv.z + bf2f(p0.z) + bf2f(p1.z);
    o.w = xv.w + bv.w + bf2f(p0.w) + bf2f(p1.w);
    *(float4*)&out[idx] = o;
}

// ---------------------------------------------------------------------------
// Transposed MFMA flash attention, split-K x4 (z: 512 keys each), 8 waves x
// 32 q = 256-q tile. Single-buffered LDS (dbuf measured neutral - issue-bound).
// Static-max exp2 softmax; P->bf16 via v_cvt_pk_bf16_f32; l via all-ones-A
// MFMA; S^T zero-init folded into first kh MFMA; setprio around MFMA clusters.
// ---------------------------------------------------------------------------
__global__ __launch_bounds__(512) void attn_mfma(
    const unsigned short* __restrict__ qb, const unsigned short* __restrict__ kb,
    const unsigned short* __restrict__ vtb,
    unsigned short* __restrict__ Op0, unsigned short* __restrict__ Op1,
    unsigned short* __restrict__ Op2, unsigned short* __restrict__ Op3,
    float* __restrict__ lp)
{
    __shared__ __align__(16) unsigned short ks[64 * 64];   // [key][d] swizzled
    __shared__ __align__(16) unsigned short vts[64 * 64];  // [d][pos] swizzled

    const int tid = threadIdx.x;
    const int lane = tid & 63, w = tid >> 6;           // 8 waves
    const int c = lane & 15, quad = lane >> 4;
    const int bh = blockIdx.y;
    const int q0 = blockIdx.x * 256;
    const int z = blockIdx.z;
    const int kk0 = z * 512;

    // Q as B-operand: lane needs Q[q0+w*32+qs*16+c][kh*32+quad*8+j]
    bf16x8 qf[2][2];   // [qs][kh]
#pragma unroll
    for (int qs = 0; qs < 2; qs++) {
        const size_t base = (((size_t)bh * 2048) + q0 + w * 32 + qs * 16 + c) * 64 + quad * 8;
        qf[qs][0] = *(const bf16x8*)&qb[base];
        qf[qs][1] = *(const bf16x8*)&qb[base + 32];
    }

    // all-ones bf16 A-operand for the l (row-sum) MFMA; persistent zero C
    bf16x8 ones;
#pragma unroll
    for (int i = 0; i < 8; i++) ones[i] = (short)0x3F80;
    const f32x4 fz = (f32x4)0.f;

    f32x4 of[2][4];
#pragma unroll
    for (int qs = 0; qs < 2; qs++)
#pragma unroll
        for (int i = 0; i < 4; i++) of[qs][i] = (f32x4)0.f;
    f32x4 lf[2];
    lf[0] = (f32x4)0.f; lf[1] = (f32x4)0.f;

    const size_t kbase = ((size_t)bh * 2048) * 64;
    const size_t vbase = ((size_t)bh * 64) * 2048;

    // stage addressing: 512 chunks of 16B per tile, one per thread
    const int srow = tid >> 3, spc = tid & 7;
    const int slc = spc ^ (srow & 7);

    for (int kk = kk0; kk < kk0 + 512; kk += 64) {
        __syncthreads();
        ld_g2l(&kb[kbase + (size_t)(kk + srow) * 64 + slc * 8], &ks[tid << 3]);
        ld_g2l(&vtb[vbase + (size_t)srow * 2048 + kk + slc * 8], &vts[tid << 3]);
        __syncthreads();

        // ---- S^T = K @ Q^T (first kh writes into zero-C, no v_mov init) ----
        f32x4 sc[2][4];
        __builtin_amdgcn_s_setprio(1);
#pragma unroll
        for (int t = 0; t < 4; t++) {
            const int phys0 = ((0 * 4 + quad) ^ (c & 7)) << 3;
            const int phys1 = ((1 * 4 + quad) ^ (c & 7)) << 3;
            bf16x8 kf0 = *(const bf16x8*)&ks[(t * 16 + c) * 64 + phys0];
            sc[0][t] = __builtin_amdgcn_mfma_f32_16x16x32_bf16(kf0, qf[0][0], fz, 0, 0, 0);
            sc[1][t] = __builtin_amdgcn_mfma_f32_16x16x32_bf16(kf0, qf[1][0], fz, 0, 0, 0);
            bf16x8 kf1 = *(const bf16x8*)&ks[(t * 16 + c) * 64 + phys1];
            sc[0][t] = __builtin_amdgcn_mfma_f32_16x16x32_bf16(kf1, qf[0][1], sc[0][t], 0, 0, 0);
            sc[1][t] = __builtin_amdgcn_mfma_f32_16x16x32_bf16(kf1, qf[1][1], sc[1][t], 0, 0, 0);
        }
        __builtin_amdgcn_s_setprio(0);

        // ---- softmax: static max, exp2 domain; pack via v_cvt_pk_bf16_f32 ----
        bf16x8 pb[2][2];
#pragma unroll
        for (int qs = 0; qs < 2; qs++) {
#pragma unroll
            for (int t = 0; t < 4; t++)
#pragma unroll
                for (int r = 0; r < 4; r++)
                    sc[qs][t][r] = exp2f(sc[qs][t][r]);
#pragma unroll
            for (int kh = 0; kh < 2; kh++) {
                union { int4 i; bf16x8 v; } u;
                u.i.x = cvt_pk_bf16(sc[qs][2 * kh][0],     sc[qs][2 * kh][1]);
                u.i.y = cvt_pk_bf16(sc[qs][2 * kh][2],     sc[qs][2 * kh][3]);
                u.i.z = cvt_pk_bf16(sc[qs][2 * kh + 1][0], sc[qs][2 * kh + 1][1]);
                u.i.w = cvt_pk_bf16(sc[qs][2 * kh + 1][2], sc[qs][2 * kh + 1][3]);
                pb[qs][kh] = u.v;
            }
        }

        // ---- l + PV on the matrix pipe ----
        __builtin_amdgcn_s_setprio(1);
#pragma unroll
        for (int qs = 0; qs < 2; qs++)
#pragma unroll
            for (int kh = 0; kh < 2; kh++)
                lf[qs] = __builtin_amdgcn_mfma_f32_16x16x32_bf16(
                    ones, pb[qs][kh], lf[qs], 0, 0, 0);

#pragma unroll
        for (int dt = 0; dt < 4; dt++) {
#pragma unroll
            for (int kh = 0; kh < 2; kh++) {
                const int phys = ((kh * 4 + quad) ^ (c & 7)) << 3;
                bf16x8 vf = *(const bf16x8*)&vts[(dt * 16 + c) * 64 + phys];
#pragma unroll
                for (int qs = 0; qs < 2; qs++)
                    of[qs][dt] = __builtin_amdgcn_mfma_f32_16x16x32_bf16(
                        vf, pb[qs][kh], of[qs][dt], 0, 0, 0);
            }
        }
        __builtin_amdgcn_s_setprio(0);
    }

    // ---- epilogue: store UNSCALED partial O (bf16) + partial l ----
    unsigned short* Op = (z == 0) ? Op0 : (z == 1) ? Op1 : (z == 2) ? Op2 : Op3;
    const int b = bh >> 4, hh = bh & 15;
#pragma unroll
    for (int qs = 0; qs < 2; qs++) {
        const int q = q0 + w * 32 + qs * 16 + c;
        if (lane < 16)
            lp[((size_t)z * 32 + bh) * 2048 + q] = lf[qs][0];
        const size_t row = (size_t)(b * 2048 + q);
#pragma unroll
        for (int dt = 0; dt < 4; dt++) {
            ushort4 o;
            o.x = f2bf(of[qs][dt][0]); o.y = f2bf(of[qs][dt][1]);
            o.z = f2bf(of[qs][dt][2]); o.w = f2bf(of[qs][dt][3]);
            *(ushort4*)&Op[row * 1024 + hh * 64 + dt * 16 + quad * 4] = o;
        }
    }
}

// ---------------------------------------------------------------------------
// merge_attn: attnb = (Op0+Op1+Op2+Op3) / (l0+l1+l2+l3), bf16 out.
// ---------------------------------------------------------------------------
__global__ __launch_bounds__(256) void merge_attn(
    const unsigned short* __restrict__ Op0, const unsigned short* __restrict__ Op1,
    const unsigned short* __restrict__ Op2, const unsigned short* __restrict__ Op3,
    const float* __restrict__ lp, unsigned short* __restrict__ attnb)
{
    const int row = blockIdx.x;
    const int b = row >> 11, s = row & 2047;
    const int tid = threadIdx.x;
    const int n = tid * 4, h = tid >> 4;
    float lsum = 0.f;
#pragma unroll
    for (int z = 0; z < 4; z++)
        lsum += lp[((size_t)z * 32 + b * 16 + h) * 2048 + s];
    const float inv = 1.f / lsum;
    const size_t off = (size_t)row * 1024 + n;
    ushort4 a0 = *(const ushort4*)&Op0[off];
    ushort4 a1 = *(const ushort4*)&Op1[off];
    ushort4 a2 = *(const ushort4*)&Op2[off];
    ushort4 a3 = *(const ushort4*)&Op3[off];
    ushort4 o;
    o.x = f2bf((bf2f(a0.x) + bf2f(a1.x) + bf2f(a2.x) + bf2f(a3.x)) * inv);
    o.y = f2bf((bf2f(a0.y) + bf2f(a1.y) + bf2f(a2.y) + bf2f(a3.y)) * inv);
    o.z = f2bf((bf2f(a0.z) + bf2f(a1.z) + bf2f(a2.z) + bf2f(a3.z)) * inv);
    o.w = f2bf((bf2f(a0.w) + bf2f(a1.w) + bf2f(a2.w) + bf2f(a3.w)) * inv);
    *(ushort4*)&attnb[off] = o;
}

// ---------------------------------------------------------------------------
// AdaLN (vectorized): x fp32, gamma/beta bf16 (stride 4096, +gboff), out bf16
// ---------------------------------------------------------------------------
__global__ __launch_bounds__(256) void adaln_bf(
    const float* __restrict__ x, const unsigned short* __restrict__ gb, int gboff,
    unsigned short* __restrict__ h)
{
    const int row = blockIdx.x;
    const float* xr = x + (size_t)row * D_MODEL;
    float4 v = ((const float4*)xr)[threadIdx.x];
    float s = v.x + v.y + v.z + v.w;
    float ss = v.x * v.x + v.y * v.y + v.z * v.z + v.w * v.w;
#pragma unroll
    for (int off = 1; off < 64; off <<= 1) {
        s  += __shfl_xor(s, off, 64);
        ss += __shfl_xor(ss, off, 64);
    }
    __shared__ float red[8];
    const int wave = threadIdx.x >> 6;
    if ((threadIdx.x & 63) == 0) { red[wave] = s; red[4 + wave] = ss; }
    __syncthreads();
    s  = red[0] + red[1] + red[2] + red[3];
    ss = red[4] + red[5] + red[6] + red[7];
    const float mu = s * (1.f / 1024.f);
    const float var = ss * (1.f / 1024.f) - mu * mu;
    const float rstd = rsqrtf(var + 1e-5f);
    const int c = threadIdx.x * 4;
    ushort4 g4 = *(const ushort4*)&gb[(size_t)row * 4096 + gboff + c];
    ushort4 b4 = *(const ushort4*)&gb[(size_t)row * 4096 + gboff + 1024 + c];
    ushort4 o;
    o.x = f2bf((v.x - mu) * rstd * (1.f + bf2f(g4.x)) + bf2f(b4.x));
    o.y = f2bf((v.y - mu) * rstd * (1.f + bf2f(g4.y)) + bf2f(b4.y));
    o.z = f2bf((v.z - mu) * rstd * (1.f + bf2f(g4.z)) + bf2f(b4.z));
    o.w = f2bf((v.w - mu) * rstd * (1.f + bf2f(g4.w)) + bf2f(b4.w));
    *(ushort4*)&h[(size_t)row * 1024 + c] = o;
}

// ---------------------------------------------------------------------------
extern "C" void kernel_launch(void* const* d_in, const int* in_sizes, int n_in,
                              void* d_out, int out_size, void* d_ws, size_t ws_size,
                              hipStream_t stream)
{
    const float* x      = (const float*)d_in[0];
    const float* cond   = (const float*)d_in[1];
    const float* p1_w   = (const float*)d_in[2];
    const float* p1_b   = (const float*)d_in[3];
    const float* qkv_w  = (const float*)d_in[4];
    const float* attn_w = (const float*)d_in[5];
    const float* p2_w   = (const float*)d_in[6];
    const float* p2_b   = (const float*)d_in[7];
    const float* ffn_w1 = (const float*)d_in[8];
    const float* ffn_b1 = (const float*)d_in[9];
    const float* ffn_w2 = (const float*)d_in[10];
    const float* ffn_b2 = (const float*)d_in[11];
    float* out = (float*)d_out;

    char* ws = (char*)d_ws;
    const size_t MB = 1024ull * 1024ull;
    unsigned short* wt_cond = (unsigned short*)(ws);             // [0,4)   dead after GB
    unsigned short* wt_qkv  = (unsigned short*)(ws + 4 * MB);    // [4,10)  dead after QKV
    unsigned short* wt_attn = (unsigned short*)(ws + 10 * MB);   // [10,12)
    unsigned short* wt_ffn1 = (unsigned short*)(ws + 12 * MB);   // [12,20)
    unsigned short* wt_ffn2 = (unsigned short*)(ws + 20 * MB);   // [20,28)
    unsigned short* siluc   = (unsigned short*)(ws + 28 * MB);   // [28,32) dead after GB
    unsigned short* gb      = (unsigned short*)(ws + 32 * MB);   // [32,64) dead after adaln#2
    unsigned short* h       = (unsigned short*)(ws + 64 * MB);   // [64,72) h1 dead after QKV
    float*          x1      = (float*)(ws + 72 * MB);            // [72,88) written by PROJ
    unsigned short* qb      = (unsigned short*)(ws + 88 * MB);   // [88,96)
    unsigned short* kb      = (unsigned short*)(ws + 96 * MB);   // [96,104)
    unsigned short* vtb     = (unsigned short*)(ws + 104 * MB);  // [104,112)
    unsigned short* attnb   = (unsigned short*)(ws + 112 * MB);  // [112,120)
    unsigned short* ff1     = (unsigned short*)(ws + 88 * MB);   // [88,120) overlay
    // attention partials, overlaying regions dead at attention time:
    unsigned short* Op0     = (unsigned short*)(ws);             // [0,8)   wt_cond+wt_qkv dead
    unsigned short* Op1     = (unsigned short*)(ws + 64 * MB);   // [64,72) h1 dead
    unsigned short* Op2     = (unsigned short*)(ws + 72 * MB);   // [72,80) x1 written later
    unsigned short* Op3     = (unsigned short*)(ws + 80 * MB);   // [80,88) x1 written later
    float*          lp      = (float*)(ws + 28 * MB);            // [28,29) siluc dead, 1MB
    // FFN2 split-K x2 bf16 partials: gb region dead by FFN2 time. [32,48)
    unsigned short* Pff     = (unsigned short*)(ws + 32 * MB);

    dim3 blk(256);

    // one dispatch: all weight transposes + silu(cond)
    prep_weights<<<dim3(4096), blk, 0, stream>>>(
        p1_w, p2_w, qkv_w, attn_w, ffn_w1, ffn_w2, cond,
        wt_cond, wt_qkv, wt_attn, wt_ffn1, wt_ffn2, siluc);

    // gb = silu(cond) @ [p1_w|p2_w] + [p1_b|p2_b]   (4096x4096, K=512)
    gemm_bf16<EPI_GB, 128><<<dim3(32, 32), blk, 0, stream>>>(
        siluc, wt_cond, p1_b, p2_b, nullptr, gb, nullptr, nullptr, nullptr, 512);
    // h1 = adaln(x, gb1)
    adaln_bf<<<NTOK, blk, 0, stream>>>(x, gb, 0, h);
    // qkv = h1 @ qkv_w  -> q/k bf16 (Q prescaled), v^T bf16 pre-permuted
    gemm_bf16<EPI_QKV, 128><<<dim3(24, 32), blk, 0, stream>>>(
        h, wt_qkv, nullptr, nullptr, nullptr, nullptr, qb, kb, vtb, 1024);
    // attention: split-K x4, 8-wave blocks -> 1024 blocks
    attn_mfma<<<dim3(SEQ / 256, 32, 4), dim3(512), 0, stream>>>(
        qb, kb, vtb, Op0, Op1, Op2, Op3, lp);
    merge_attn<<<dim3(NTOK), blk, 0, stream>>>(Op0, Op1, Op2, Op3, lp, attnb);
    // x1 = x + attn @ attn_out_w   (BM=64 dbuf -> 512 blocks)
    gemm_bf16<EPI_PROJ, 64, true><<<dim3(8, 64), blk, 0, stream>>>(
        attnb, wt_attn, nullptr, nullptr, x, x1, nullptr, nullptr, nullptr, 1024);
    // h2 = adaln(x1, gb2)
    adaln_bf<<<NTOK, blk, 0, stream>>>(x1, gb, 2048, h);
    // ff1 = gelu_tanh(h2 @ ffn_w1 + b1)
    gemm_bf16<EPI_FFN1, 128><<<dim3(32, 32), blk, 0, stream>>>(
        h, wt_ffn1, ffn_b1, nullptr, nullptr, ff1, nullptr, nullptr, nullptr, 1024);
    // FFN2: BM=128 (m97 density) + split-K x2 + dbuf -> 512 blocks, 2/CU
    gemm_bf16<EPI_PART, 128, true, 2><<<dim3(8, 32, 2), blk, 0, stream>>>(
        ff1, wt_ffn2, nullptr, nullptr, nullptr, Pff, nullptr, nullptr, nullptr, 4096);
    // out = x1 + b2 + Pff[0] + Pff[1]
    merge_ffn2<<<dim3(4096), blk, 0, stream>>>(Pff, x1, ffn_b2, out);
}

// Round 6
// 374.445 us; speedup vs baseline: 1.0666x; 1.0227x over previous
//
#include <hip/hip_runtime.h>
#include <math.h>

#define D_MODEL 1024
#define SEQ 2048
#define NTOK 4096

typedef __attribute__((ext_vector_type(8))) short bf16x8;
typedef __attribute__((ext_vector_type(4))) float f32x4;

// manual RNE f32->bf16 (KEEP for all GEMM-feeding / output conversions:
// v_cvt_pk_bf16_f32 truncates (RTZ) — its systematic bias through the
// K=4096 FFN2 reduction produced absmax 0.94 in round 5)
__device__ __forceinline__ unsigned short f2bf(float f) {
    union { float f; unsigned u; } v; v.f = f;
    unsigned r = v.u + 0x7FFFu + ((v.u >> 16) & 1u);   // RNE
    return (unsigned short)(r >> 16);
}
__device__ __forceinline__ float bf2f(unsigned short u) {
    union { unsigned u; float f; } v; v.u = ((unsigned)u) << 16; return v.f;
}
// pack two fp32 -> bf16x2, 1 VALU op. ONLY safe where truncation bias
// self-cancels (attention P: l is computed from the same packed P).
__device__ __forceinline__ unsigned cvt_pk_bf16(float x, float y) {
    unsigned r;
    asm("v_cvt_pk_bf16_f32 %0, %1, %2" : "=v"(r) : "v"(x), "v"(y));
    return r;
}
// raw hardware 2^x (~1 ULP) — avoids libm exp2f's range-fixup instruction bloat
__device__ __forceinline__ float ex2(float x) {
#if __has_builtin(__builtin_amdgcn_exp2f)
    return __builtin_amdgcn_exp2f(x);
#else
    float r; asm("v_exp_f32 %0, %1" : "=v"(r) : "v"(x)); return r;
#endif
}
#define LOG2E 1.44269504088896340736f

// async global->LDS, 16B per lane. LDS dest must be wave-uniform base + lane*16.
__device__ __forceinline__ void ld_g2l(const void* g, void* l) {
    __builtin_amdgcn_global_load_lds(
        (const __attribute__((address_space(1))) void*)g,
        (__attribute__((address_space(3))) void*)l, 16, 0, 0);
}

// ---------------------------------------------------------------------------
// prep_weights: ONE dispatch does all 6 fp32[K,N]->bf16[N,K] transposes
// plus silu(cond)->bf16.
// ---------------------------------------------------------------------------
__global__ __launch_bounds__(256) void prep_weights(
    const float* __restrict__ p1, const float* __restrict__ p2,
    const float* __restrict__ qkvw, const float* __restrict__ attnw,
    const float* __restrict__ f1, const float* __restrict__ f2,
    const float* __restrict__ cond,
    unsigned short* __restrict__ wt_cond, unsigned short* __restrict__ wt_qkv,
    unsigned short* __restrict__ wt_attn, unsigned short* __restrict__ wt_ffn1,
    unsigned short* __restrict__ wt_ffn2, unsigned short* __restrict__ siluc)
{
    const int t = blockIdx.x;
    if (t >= 3584) {   // silu path: 512 blocks x 1024 float4
        const int base = (t - 3584) * 1024 + threadIdx.x;
#pragma unroll
        for (int i = 0; i < 4; i++) {
            const int idx = base + i * 256;
            float4 v = ((const float4*)cond)[idx];
            // silu(x) = x / (1 + 2^(-x*log2e)), raw v_exp; RNE pack
            ushort4 o;
            o.x = f2bf(v.x / (1.f + ex2(-v.x * LOG2E)));
            o.y = f2bf(v.y / (1.f + ex2(-v.y * LOG2E)));
            o.z = f2bf(v.z / (1.f + ex2(-v.z * LOG2E)));
            o.w = f2bf(v.w / (1.f + ex2(-v.w * LOG2E)));
            ((ushort4*)siluc)[idx] = o;
        }
        return;
    }
    const float* src; unsigned short* dst; int K, N, lt;
    if (t < 512)       { src = (t < 256) ? p1 : p2;
                         dst = wt_cond + (t < 256 ? 0 : 2048 * 512);
                         K = 512;  N = 2048; lt = t & 255; }
    else if (t < 1280) { src = qkvw;  dst = wt_qkv;  K = 1024; N = 3072; lt = t - 512; }
    else if (t < 1536) { src = attnw; dst = wt_attn; K = 1024; N = 1024; lt = t - 1280; }
    else if (t < 2560) { src = f1;    dst = wt_ffn1; K = 1024; N = 4096; lt = t - 1536; }
    else               { src = f2;    dst = wt_ffn2; K = 4096; N = 1024; lt = t - 2560; }
    const int ntile = N >> 6;
    const int n0 = (lt % ntile) * 64, k0 = (lt / ntile) * 64;

    __shared__ float tile[64][65];
    const int tx = threadIdx.x & 15, ty = threadIdx.x >> 4;
#pragma unroll
    for (int i = 0; i < 4; i++) {
        const int k = ty + i * 16;
        float4 v = *(const float4*)&src[(size_t)(k0 + k) * N + n0 + tx * 4];
        tile[k][tx * 4 + 0] = v.x; tile[k][tx * 4 + 1] = v.y;
        tile[k][tx * 4 + 2] = v.z; tile[k][tx * 4 + 3] = v.w;
    }
    __syncthreads();
#pragma unroll
    for (int i = 0; i < 4; i++) {
        const int n = ty + i * 16;
        ushort4 o;
        o.x = f2bf(tile[tx * 4 + 0][n]); o.y = f2bf(tile[tx * 4 + 1][n]);
        o.z = f2bf(tile[tx * 4 + 2][n]); o.w = f2bf(tile[tx * 4 + 3][n]);
        *(ushort4*)&dst[(size_t)(n0 + n) * K + k0 + tx * 4] = o;
    }
}

// ---------------------------------------------------------------------------
// bf16 MFMA GEMM: C = epi(A[M,K] @ Bt[N,K]^T). BM x 128 tile, BK=64,
// 4 waves (2x2), 16x16x32 MFMA, global_load_lds staging, XOR swizzle.
// DBUF: double-buffered LDS, single barrier per K-step.
// SPLIT>1: grid.z splits K; EPI_PART writes bf16 partials (merge_ffn2 sums).
// ---------------------------------------------------------------------------
#define EPI_GB   0
#define EPI_QKV  1
#define EPI_PROJ 2
#define EPI_FFN1 3
#define EPI_FFN2 4
#define EPI_PART 5

template<int EPI, int BM, bool DBUF = false, int SPLIT = 1>
__global__ __launch_bounds__(256, 4) void gemm_bf16(
    const unsigned short* __restrict__ A,
    const unsigned short* __restrict__ Bt,
    const float* __restrict__ bias, const float* __restrict__ bias2,
    const float* __restrict__ res,
    void* __restrict__ Cv,
    unsigned short* __restrict__ qb, unsigned short* __restrict__ kb,
    unsigned short* __restrict__ vtb,
    int K)
{
    constexpr int WM = BM / 2;     // 64 or 32
    constexpr int MT = WM / 16;    // 4 or 2
    constexpr int NB = DBUF ? 2 : 1;
    __shared__ __align__(16) unsigned short As[NB][BM * 64];
    __shared__ __align__(16) unsigned short Bs[NB][128 * 64];
    const int tid = threadIdx.x;
    const int lane = tid & 63, w = tid >> 6;
    const int cc = lane & 15, quad = lane >> 4;
    const int wm = (w >> 1) * WM, wn = (w & 1) * 64;
    const int m0 = blockIdx.y * BM, n0 = blockIdx.x * 128;
    const int kslice = K / SPLIT;
    const int kbeg = (SPLIT > 1) ? (int)blockIdx.z * kslice : 0;

    f32x4 acc[MT][4];
#pragma unroll
    for (int i = 0; i < MT; i++)
#pragma unroll
        for (int j = 0; j < 4; j++) acc[i][j] = (f32x4)0.f;

    auto stage = [&](int buf, int k0) {
#pragma unroll
        for (int i = 0; i < BM / 32; i++) {
            const int idx = i * 256 + tid;
            const int row = idx >> 3, c = idx & 7;
            const int kc = (c ^ (row & 7)) << 3;
            ld_g2l(&A[(size_t)(m0 + row) * K + k0 + kc], &As[buf][idx << 3]);
        }
#pragma unroll
        for (int i = 0; i < 4; i++) {
            const int idx = i * 256 + tid;
            const int row = idx >> 3, c = idx & 7;
            const int kc = (c ^ (row & 7)) << 3;
            ld_g2l(&Bt[(size_t)(n0 + row) * K + k0 + kc], &Bs[buf][idx << 3]);
        }
    };
    auto compute = [&](int buf) {
#pragma unroll
        for (int ks = 0; ks < 2; ks++) {
            bf16x8 af[MT], bfr[4];
            const int pc = (((ks << 2) | quad) ^ (cc & 7)) << 3;
#pragma unroll
            for (int t = 0; t < MT; t++)
                af[t]  = *(const bf16x8*)&As[buf][(wm + t * 16 + cc) * 64 + pc];
#pragma unroll
            for (int t = 0; t < 4; t++)
                bfr[t] = *(const bf16x8*)&Bs[buf][(wn + t * 16 + cc) * 64 + pc];
#pragma unroll
            for (int mt = 0; mt < MT; mt++)
#pragma unroll
                for (int nt = 0; nt < 4; nt++)
                    acc[mt][nt] = __builtin_amdgcn_mfma_f32_16x16x32_bf16(
                        af[mt], bfr[nt], acc[mt][nt], 0, 0, 0);
        }
    };

    if (DBUF) {
        stage(0, kbeg);
        int cur = 0;
        for (int k0 = kbeg; k0 < kbeg + kslice; k0 += 64) {
            __syncthreads();            // drains this buf's stage + prev reads
            if (k0 + 64 < kbeg + kslice) stage(cur ^ 1, k0 + 64);
            compute(cur);
            cur ^= 1;
        }
    } else {
        for (int k0 = kbeg; k0 < kbeg + kslice; k0 += 64) {
            __syncthreads();
            stage(0, k0);
            __syncthreads();
            compute(0);
        }
    }

    // ---- epilogues. C-frag: row = quad*4+r, col = cc ----
    if (EPI == EPI_GB) {
        unsigned short* C = (unsigned short*)Cv;
#pragma unroll
        for (int mt = 0; mt < MT; mt++)
#pragma unroll
        for (int r = 0; r < 4; r++) {
            const int m = m0 + wm + mt * 16 + quad * 4 + r;
#pragma unroll
            for (int nt = 0; nt < 4; nt++) {
                const int n = n0 + wn + nt * 16 + cc;
                const float b = (n < 2048) ? bias[n] : bias2[n - 2048];
                C[(size_t)m * 4096 + n] = f2bf(acc[mt][nt][r] + b);
            }
        }
    } else if (EPI == EPI_PROJ) {
        float* C = (float*)Cv;
#pragma unroll
        for (int mt = 0; mt < MT; mt++)
#pragma unroll
        for (int r = 0; r < 4; r++) {
            const int m = m0 + wm + mt * 16 + quad * 4 + r;
#pragma unroll
            for (int nt = 0; nt < 4; nt++) {
                const int n = n0 + wn + nt * 16 + cc;
                C[(size_t)m * 1024 + n] = acc[mt][nt][r] + res[(size_t)m * 1024 + n];
            }
        }
    } else if (EPI == EPI_FFN1) {
        unsigned short* C = (unsigned short*)Cv;
#pragma unroll
        for (int mt = 0; mt < MT; mt++)
#pragma unroll
        for (int r = 0; r < 4; r++) {
            const int m = m0 + wm + mt * 16 + quad * 4 + r;
#pragma unroll
            for (int nt = 0; nt < 4; nt++) {
                const int n = n0 + wn + nt * 16 + cc;
                float v = acc[mt][nt][r] + bias[n];
                // tanh-approx GELU: x / (1 + exp2(-2.3022084*(x + 0.044715 x^3)))
                const float u = v + 0.044715f * v * v * v;
                const float g = v / (1.f + ex2(-2.3022084f * u));
                C[(size_t)m * 4096 + n] = f2bf(g);
            }
        }
    } else if (EPI == EPI_PART) {
        // bf16 partial: Cv + z * M*1024
        unsigned short* C = (unsigned short*)Cv + (size_t)blockIdx.z * (4096ull * 1024ull);
#pragma unroll
        for (int mt = 0; mt < MT; mt++)
#pragma unroll
        for (int r = 0; r < 4; r++) {
            const int m = m0 + wm + mt * 16 + quad * 4 + r;
#pragma unroll
            for (int nt = 0; nt < 4; nt++) {
                const int n = n0 + wn + nt * 16 + cc;
                C[(size_t)m * 1024 + n] = f2bf(acc[mt][nt][r]);
            }
        }
    } else if (EPI == EPI_FFN2) {
        float* C = (float*)Cv;
#pragma unroll
        for (int mt = 0; mt < MT; mt++)
#pragma unroll
        for (int r = 0; r < 4; r++) {
            const int m = m0 + wm + mt * 16 + quad * 4 + r;
#pragma unroll
            for (int nt = 0; nt < 4; nt++) {
                const int n = n0 + wn + nt * 16 + cc;
                C[(size_t)m * 1024 + n] = acc[mt][nt][r] + bias[n] + res[(size_t)m * 1024 + n];
            }
        }
    } else {  // EPI_QKV: N=3072, split q/k bf16 + PERMUTED v^T bf16
        const int region = n0 >> 10;
        const int b = m0 >> 11;
        if (region < 2) {
            unsigned short* dst = region ? kb : qb;
            // Q prescale folds softmax 1/sqrt(d) AND log2(e)
            const float sc = region ? 1.0f : 0.125f * LOG2E;
#pragma unroll
            for (int mt = 0; mt < MT; mt++)
#pragma unroll
            for (int r = 0; r < 4; r++) {
                const int m = m0 + wm + mt * 16 + quad * 4 + r;
                const int s = m & 2047;
#pragma unroll
                for (int nt = 0; nt < 4; nt++) {
                    const int n = (n0 + wn + nt * 16 + cc) & 1023;
                    const int hh = n >> 6, d = n & 63;
                    dst[(((size_t)b * 16 + hh) * 2048 + s) * 64 + d] =
                        f2bf(acc[mt][nt][r] * sc);
                }
            }
        } else {
            // V^T stored pre-permuted into PV B-fragment key order
            const int sb = (m0 + wm) & 2047;
#pragma unroll
            for (int mt = 0; mt < MT; mt++) {
                const int kpos = sb + ((mt >> 1) << 5) + (quad << 3) + ((mt & 1) << 2);
#pragma unroll
                for (int nt = 0; nt < 4; nt++) {
                    const int n = (n0 + wn + nt * 16 + cc) & 1023;
                    const int hh = n >> 6, d = n & 63;
                    ushort4 o;
                    o.x = f2bf(acc[mt][nt][0]); o.y = f2bf(acc[mt][nt][1]);
                    o.z = f2bf(acc[mt][nt][2]); o.w = f2bf(acc[mt][nt][3]);
                    *(ushort4*)&vtb[(((size_t)b * 16 + hh) * 64 + d) * 2048 + kpos] = o;
                }
            }
        }
    }
}

// ---------------------------------------------------------------------------
// merge_ffn2: out = x1 + b2 + sum_z P[z]   (P bf16 partials x2, out fp32)
// ---------------------------------------------------------------------------
__global__ __launch_bounds__(256) void merge_ffn2(
    const unsigned short* __restrict__ P, const float* __restrict__ x1,
    const float* __restrict__ b2, float* __restrict__ out)
{
    const size_t idx = (size_t)blockIdx.x * 1024 + (size_t)threadIdx.x * 4;
    const int n = (int)(idx & 1023);
    float4 xv = *(const float4*)&x1[idx];
    float4 bv = *(const float4*)&b2[n];
    ushort4 p0 = *(const ushort4*)&P[idx];
    ushort4 p1 = *(const ushort4*)&P[(4096ull * 1024ull) + idx];
    float4 o;
    o.x = xv.x + bv.x + bf2f(p0.x) + bf2f(p1.x);
    o.y = xv.y + bv.y + bf2f(p0.y) + bf2f(p1.y);
    o.z = xv.z + bv.z + bf2f(p0.z) + bf2f(p1.z);
    o.w = xv.w + bv.w + bf2f(p0.w) + bf2f(p1.w);
    *(float4*)&out[idx] = o;
}

// ---------------------------------------------------------------------------
// Transposed MFMA flash attention, split-K x4 (z: 512 keys each), 8 waves x
// 32 q = 256-q tile. Static-max exp2 softmax (raw v_exp_f32); P->bf16 via
// v_cvt_pk_bf16_f32 (bias self-cancels via l); l via all-ones-A MFMA;
// zero-fold S^T init; setprio around MFMA clusters.
// ---------------------------------------------------------------------------
__global__ __launch_bounds__(512) void attn_mfma(
    const unsigned short* __restrict__ qb, const unsigned short* __restrict__ kb,
    const unsigned short* __restrict__ vtb,
    unsigned short* __restrict__ Op0, unsigned short* __restrict__ Op1,
    unsigned short* __restrict__ Op2, unsigned short* __restrict__ Op3,
    float* __restrict__ lp)
{
    __shared__ __align__(16) unsigned short ks[64 * 64];   // [key][d] swizzled
    __shared__ __align__(16) unsigned short vts[64 * 64];  // [d][pos] swizzled

    const int tid = threadIdx.x;
    const int lane = tid & 63, w = tid >> 6;           // 8 waves
    const int c = lane & 15, quad = lane >> 4;
    const int bh = blockIdx.y;
    const int q0 = blockIdx.x * 256;
    const int z = blockIdx.z;
    const int kk0 = z * 512;

    // Q as B-operand: lane needs Q[q0+w*32+qs*16+c][kh*32+quad*8+j]
    bf16x8 qf[2][2];   // [qs][kh]
#pragma unroll
    for (int qs = 0; qs < 2; qs++) {
        const size_t base = (((size_t)bh * 2048) + q0 + w * 32 + qs * 16 + c) * 64 + quad * 8;
        qf[qs][0] = *(const bf16x8*)&qb[base];
        qf[qs][1] = *(const bf16x8*)&qb[base + 32];
    }

    // all-ones bf16 A-operand for the l (row-sum) MFMA; persistent zero C
    bf16x8 ones;
#pragma unroll
    for (int i = 0; i < 8; i++) ones[i] = (short)0x3F80;
    const f32x4 fz = (f32x4)0.f;

    f32x4 of[2][4];
#pragma unroll
    for (int qs = 0; qs < 2; qs++)
#pragma unroll
        for (int i = 0; i < 4; i++) of[qs][i] = (f32x4)0.f;
    f32x4 lf[2];
    lf[0] = (f32x4)0.f; lf[1] = (f32x4)0.f;

    const size_t kbase = ((size_t)bh * 2048) * 64;
    const size_t vbase = ((size_t)bh * 64) * 2048;

    // stage addressing: 512 chunks of 16B per tile, one per thread
    const int srow = tid >> 3, spc = tid & 7;
    const int slc = spc ^ (srow & 7);

    for (int kk = kk0; kk < kk0 + 512; kk += 64) {
        __syncthreads();
        ld_g2l(&kb[kbase + (size_t)(kk + srow) * 64 + slc * 8], &ks[tid << 3]);
        ld_g2l(&vtb[vbase + (size_t)srow * 2048 + kk + slc * 8], &vts[tid << 3]);
        __syncthreads();

        // ---- S^T = K @ Q^T (first kh writes into zero-C, no v_mov init) ----
        f32x4 sc[2][4];
        __builtin_amdgcn_s_setprio(1);
#pragma unroll
        for (int t = 0; t < 4; t++) {
            const int phys0 = ((0 * 4 + quad) ^ (c & 7)) << 3;
            const int phys1 = ((1 * 4 + quad) ^ (c & 7)) << 3;
            bf16x8 kf0 = *(const bf16x8*)&ks[(t * 16 + c) * 64 + phys0];
            sc[0][t] = __builtin_amdgcn_mfma_f32_16x16x32_bf16(kf0, qf[0][0], fz, 0, 0, 0);
            sc[1][t] = __builtin_amdgcn_mfma_f32_16x16x32_bf16(kf0, qf[1][0], fz, 0, 0, 0);
            bf16x8 kf1 = *(const bf16x8*)&ks[(t * 16 + c) * 64 + phys1];
            sc[0][t] = __builtin_amdgcn_mfma_f32_16x16x32_bf16(kf1, qf[0][1], sc[0][t], 0, 0, 0);
            sc[1][t] = __builtin_amdgcn_mfma_f32_16x16x32_bf16(kf1, qf[1][1], sc[1][t], 0, 0, 0);
        }
        __builtin_amdgcn_s_setprio(0);

        // ---- softmax: static max, exp2 domain (raw v_exp); pack via cvt_pk ----
        bf16x8 pb[2][2];
#pragma unroll
        for (int qs = 0; qs < 2; qs++) {
#pragma unroll
            for (int t = 0; t < 4; t++)
#pragma unroll
                for (int r = 0; r < 4; r++)
                    sc[qs][t][r] = ex2(sc[qs][t][r]);
#pragma unroll
            for (int kh = 0; kh < 2; kh++) {
                union { int4 i; bf16x8 v; } u;
                u.i.x = cvt_pk_bf16(sc[qs][2 * kh][0],     sc[qs][2 * kh][1]);
                u.i.y = cvt_pk_bf16(sc[qs][2 * kh][2],     sc[qs][2 * kh][3]);
                u.i.z = cvt_pk_bf16(sc[qs][2 * kh + 1][0], sc[qs][2 * kh + 1][1]);
                u.i.w = cvt_pk_bf16(sc[qs][2 * kh + 1][2], sc[qs][2 * kh + 1][3]);
                pb[qs][kh] = u.v;
            }
        }

        // ---- l + PV on the matrix pipe ----
        __builtin_amdgcn_s_setprio(1);
#pragma unroll
        for (int qs = 0; qs < 2; qs++)
#pragma unroll
            for (int kh = 0; kh < 2; kh++)
                lf[qs] = __builtin_amdgcn_mfma_f32_16x16x32_bf16(
                    ones, pb[qs][kh], lf[qs], 0, 0, 0);

#pragma unroll
        for (int dt = 0; dt < 4; dt++) {
#pragma unroll
            for (int kh = 0; kh < 2; kh++) {
                const int phys = ((kh * 4 + quad) ^ (c & 7)) << 3;
                bf16x8 vf = *(const bf16x8*)&vts[(dt * 16 + c) * 64 + phys];
#pragma unroll
                for (int qs = 0; qs < 2; qs++)
                    of[qs][dt] = __builtin_amdgcn_mfma_f32_16x16x32_bf16(
                        vf, pb[qs][kh], of[qs][dt], 0, 0, 0);
            }
        }
        __builtin_amdgcn_s_setprio(0);
    }

    // ---- epilogue: store UNSCALED partial O (bf16, RNE) + partial l ----
    unsigned short* Op = (z == 0) ? Op0 : (z == 1) ? Op1 : (z == 2) ? Op2 : Op3;
    const int b = bh >> 4, hh = bh & 15;
#pragma unroll
    for (int qs = 0; qs < 2; qs++) {
        const int q = q0 + w * 32 + qs * 16 + c;
        if (lane < 16)
            lp[((size_t)z * 32 + bh) * 2048 + q] = lf[qs][0];
        const size_t row = (size_t)(b * 2048 + q);
#pragma unroll
        for (int dt = 0; dt < 4; dt++) {
            ushort4 o;
            o.x = f2bf(of[qs][dt][0]); o.y = f2bf(of[qs][dt][1]);
            o.z = f2bf(of[qs][dt][2]); o.w = f2bf(of[qs][dt][3]);
            *(ushort4*)&Op[row * 1024 + hh * 64 + dt * 16 + quad * 4] = o;
        }
    }
}

// ---------------------------------------------------------------------------
// merge_attn: attnb = (Op0+Op1+Op2+Op3) / (l0+l1+l2+l3), bf16 out.
// ---------------------------------------------------------------------------
__global__ __launch_bounds__(256) void merge_attn(
    const unsigned short* __restrict__ Op0, const unsigned short* __restrict__ Op1,
    const unsigned short* __restrict__ Op2, const unsigned short* __restrict__ Op3,
    const float* __restrict__ lp, unsigned short* __restrict__ attnb)
{
    const int row = blockIdx.x;
    const int b = row >> 11, s = row & 2047;
    const int tid = threadIdx.x;
    const int n = tid * 4, h = tid >> 4;
    float lsum = 0.f;
#pragma unroll
    for (int z = 0; z < 4; z++)
        lsum += lp[((size_t)z * 32 + b * 16 + h) * 2048 + s];
    const float inv = 1.f / lsum;
    const size_t off = (size_t)row * 1024 + n;
    ushort4 a0 = *(const ushort4*)&Op0[off];
    ushort4 a1 = *(const ushort4*)&Op1[off];
    ushort4 a2 = *(const ushort4*)&Op2[off];
    ushort4 a3 = *(const ushort4*)&Op3[off];
    ushort4 o;
    o.x = f2bf((bf2f(a0.x) + bf2f(a1.x) + bf2f(a2.x) + bf2f(a3.x)) * inv);
    o.y = f2bf((bf2f(a0.y) + bf2f(a1.y) + bf2f(a2.y) + bf2f(a3.y)) * inv);
    o.z = f2bf((bf2f(a0.z) + bf2f(a1.z) + bf2f(a2.z) + bf2f(a3.z)) * inv);
    o.w = f2bf((bf2f(a0.w) + bf2f(a1.w) + bf2f(a2.w) + bf2f(a3.w)) * inv);
    *(ushort4*)&attnb[off] = o;
}

// ---------------------------------------------------------------------------
// AdaLN (vectorized): x fp32, gamma/beta bf16 (stride 4096, +gboff), out bf16
// ---------------------------------------------------------------------------
__global__ __launch_bounds__(256) void adaln_bf(
    const float* __restrict__ x, const unsigned short* __restrict__ gb, int gboff,
    unsigned short* __restrict__ h)
{
    const int row = blockIdx.x;
    const float* xr = x + (size_t)row * D_MODEL;
    float4 v = ((const float4*)xr)[threadIdx.x];
    float s = v.x + v.y + v.z + v.w;
    float ss = v.x * v.x + v.y * v.y + v.z * v.z + v.w * v.w;
#pragma unroll
    for (int off = 1; off < 64; off <<= 1) {
        s  += __shfl_xor(s, off, 64);
        ss += __shfl_xor(ss, off, 64);
    }
    __shared__ float red[8];
    const int wave = threadIdx.x >> 6;
    if ((threadIdx.x & 63) == 0) { red[wave] = s; red[4 + wave] = ss; }
    __syncthreads();
    s  = red[0] + red[1] + red[2] + red[3];
    ss = red[4] + red[5] + red[6] + red[7];
    const float mu = s * (1.f / 1024.f);
    const float var = ss * (1.f / 1024.f) - mu * mu;
    const float rstd = rsqrtf(var + 1e-5f);
    const int c = threadIdx.x * 4;
    ushort4 g4 = *(const ushort4*)&gb[(size_t)row * 4096 + gboff + c];
    ushort4 b4 = *(const ushort4*)&gb[(size_t)row * 4096 + gboff + 1024 + c];
    ushort4 o;
    o.x = f2bf((v.x - mu) * rstd * (1.f + bf2f(g4.x)) + bf2f(b4.x));
    o.y = f2bf((v.y - mu) * rstd * (1.f + bf2f(g4.y)) + bf2f(b4.y));
    o.z = f2bf((v.z - mu) * rstd * (1.f + bf2f(g4.z)) + bf2f(b4.z));
    o.w = f2bf((v.w - mu) * rstd * (1.f + bf2f(g4.w)) + bf2f(b4.w));
    *(ushort4*)&h[(size_t)row * 1024 + c] = o;
}

// ---------------------------------------------------------------------------
extern "C" void kernel_launch(void* const* d_in, const int* in_sizes, int n_in,
                              void* d_out, int out_size, void* d_ws, size_t ws_size,
                              hipStream_t stream)
{
    const float* x      = (const float*)d_in[0];
    const float* cond   = (const float*)d_in[1];
    const float* p1_w   = (const float*)d_in[2];
    const float* p1_b   = (const float*)d_in[3];
    const float* qkv_w  = (const float*)d_in[4];
    const float* attn_w = (const float*)d_in[5];
    const float* p2_w   = (const float*)d_in[6];
    const float* p2_b   = (const float*)d_in[7];
    const float* ffn_w1 = (const float*)d_in[8];
    const float* ffn_b1 = (const float*)d_in[9];
    const float* ffn_w2 = (const float*)d_in[10];
    const float* ffn_b2 = (const float*)d_in[11];
    float* out = (float*)d_out;

    char* ws = (char*)d_ws;
    const size_t MB = 1024ull * 1024ull;
    unsigned short* wt_cond = (unsigned short*)(ws);             // [0,4)   dead after GB
    unsigned short* wt_qkv  = (unsigned short*)(ws + 4 * MB);    // [4,10)  dead after QKV
    unsigned short* wt_attn = (unsigned short*)(ws + 10 * MB);   // [10,12)
    unsigned short* wt_ffn1 = (unsigned short*)(ws + 12 * MB);   // [12,20)
    unsigned short* wt_ffn2 = (unsigned short*)(ws + 20 * MB);   // [20,28)
    unsigned short* siluc   = (unsigned short*)(ws + 28 * MB);   // [28,32) dead after GB
    unsigned short* gb      = (unsigned short*)(ws + 32 * MB);   // [32,64) dead after adaln#2
    unsigned short* h       = (unsigned short*)(ws + 64 * MB);   // [64,72) h1 dead after QKV
    float*          x1      = (float*)(ws + 72 * MB);            // [72,88) written by PROJ
    unsigned short* qb      = (unsigned short*)(ws + 88 * MB);   // [88,96)
    unsigned short* kb      = (unsigned short*)(ws + 96 * MB);   // [96,104)
    unsigned short* vtb     = (unsigned short*)(ws + 104 * MB);  // [104,112)
    unsigned short* attnb   = (unsigned short*)(ws + 112 * MB);  // [112,120)
    unsigned short* ff1     = (unsigned short*)(ws + 88 * MB);   // [88,120) overlay
    // attention partials, overlaying regions dead at attention time:
    unsigned short* Op0     = (unsigned short*)(ws);             // [0,8)   wt_cond+wt_qkv dead
    unsigned short* Op1     = (unsigned short*)(ws + 64 * MB);   // [64,72) h1 dead
    unsigned short* Op2     = (unsigned short*)(ws + 72 * MB);   // [72,80) x1 written later
    unsigned short* Op3     = (unsigned short*)(ws + 80 * MB);   // [80,88) x1 written later
    float*          lp      = (float*)(ws + 28 * MB);            // [28,29) siluc dead, 1MB
    // FFN2 split-K x2 bf16 partials: gb region dead by FFN2 time. [32,48)
    unsigned short* Pff     = (unsigned short*)(ws + 32 * MB);

    dim3 blk(256);

    // one dispatch: all weight transposes + silu(cond)
    prep_weights<<<dim3(4096), blk, 0, stream>>>(
        p1_w, p2_w, qkv_w, attn_w, ffn_w1, ffn_w2, cond,
        wt_cond, wt_qkv, wt_attn, wt_ffn1, wt_ffn2, siluc);

    // gb = silu(cond) @ [p1_w|p2_w] + [p1_b|p2_b]   (4096x4096, K=512)
    gemm_bf16<EPI_GB, 128><<<dim3(32, 32), blk, 0, stream>>>(
        siluc, wt_cond, p1_b, p2_b, nullptr, gb, nullptr, nullptr, nullptr, 512);
    // h1 = adaln(x, gb1)
    adaln_bf<<<NTOK, blk, 0, stream>>>(x, gb, 0, h);
    // qkv = h1 @ qkv_w  -> q/k bf16 (Q prescaled), v^T bf16 pre-permuted
    gemm_bf16<EPI_QKV, 128><<<dim3(24, 32), blk, 0, stream>>>(
        h, wt_qkv, nullptr, nullptr, nullptr, nullptr, qb, kb, vtb, 1024);
    // attention: split-K x4, 8-wave blocks -> 1024 blocks
    attn_mfma<<<dim3(SEQ / 256, 32, 4), dim3(512), 0, stream>>>(
        qb, kb, vtb, Op0, Op1, Op2, Op3, lp);
    merge_attn<<<dim3(NTOK), blk, 0, stream>>>(Op0, Op1, Op2, Op3, lp, attnb);
    // x1 = x + attn @ attn_out_w   (BM=64 dbuf -> 512 blocks)
    gemm_bf16<EPI_PROJ, 64, true><<<dim3(8, 64), blk, 0, stream>>>(
        attnb, wt_attn, nullptr, nullptr, x, x1, nullptr, nullptr, nullptr, 1024);
    // h2 = adaln(x1, gb2)
    adaln_bf<<<NTOK, blk, 0, stream>>>(x1, gb, 2048, h);
    // ff1 = gelu_tanh(h2 @ ffn_w1 + b1)
    gemm_bf16<EPI_FFN1, 128><<<dim3(32, 32), blk, 0, stream>>>(
        h, wt_ffn1, ffn_b1, nullptr, nullptr, ff1, nullptr, nullptr, nullptr, 1024);
    // FFN2: BM=128 (m97 density) + split-K x2 + dbuf -> 512 blocks, 2/CU
    gemm_bf16<EPI_PART, 128, true, 2><<<dim3(8, 32, 2), blk, 0, stream>>>(
        ff1, wt_ffn2, nullptr, nullptr, nullptr, Pff, nullptr, nullptr, nullptr, 4096);
    // out = x1 + b2 + Pff[0] + Pff[1]
    merge_ffn2<<<dim3(4096), blk, 0, stream>>>(Pff, x1, ffn_b2, out);
}